// Round 10
// baseline (132.891 us; speedup 1.0000x reference)
//
#include <hip/hip_runtime.h>
#include <hip/hip_bf16.h>

typedef unsigned short u16;
typedef __attribute__((ext_vector_type(8))) short short8;
typedef __attribute__((ext_vector_type(4))) float f32x4;
typedef __attribute__((ext_vector_type(4))) unsigned int u32x4;

#define CC    128
#define WW    48
#define HW2   2304      // 48*48
#define NHW   46
#define NQ    2116      // 46*46
#define NPIX  2304      // pixels per image
#define SETSZ ((size_t)NPIX * NPIX)   // D elems per candidate set
#define BATCH 2

__device__ __forceinline__ u16 f2bf(float f) {
  union { float f; unsigned u; } x; x.f = f;
  unsigned r = (x.u + 0x7fffu + ((x.u >> 16) & 1u)) >> 16;
  return (u16)r;
}
__device__ __forceinline__ float b2f(u16 v) {
  union { unsigned u; float f; } x; x.u = ((unsigned)v) << 16;
  return x.f;
}

// ---- kernel 1: per-pixel normalize + transpose to [pix][128c] bf16, chunk-swizzled ----
__global__ __launch_bounds__(256) void k_norm(const float* __restrict__ pred,
                                              const float* __restrict__ targ,
                                              u16* __restrict__ PnT, u16* __restrict__ TnT) {
  const int img = blockIdx.y;          // 0..5 : 0-1 pred, 2-5 target
  const int p0  = blockIdx.x * 64;     // 36 blocks of 64 pixels
  const int tid = threadIdx.x;
  const float* src = img < 2 ? pred + (size_t)img * CC * HW2
                             : targ + (size_t)(img - 2) * CC * HW2;
  u16* out = img < 2 ? PnT + (size_t)img * NPIX * CC
                     : TnT + (size_t)(img - 2) * NPIX * CC;

  __shared__ float sT[64][129];
  __shared__ float sInv[64];

  #pragma unroll
  for (int it = 0; it < 32; ++it) {
    int idx = it * 256 + tid;
    int c = idx >> 6, p = idx & 63;
    sT[p][c] = src[(size_t)c * HW2 + p0 + p];
  }
  __syncthreads();
  if (tid < 64) {
    float s = 0.f;
    for (int c = 0; c < CC; ++c) { float v = sT[tid][c]; s += v * v; }
    sInv[tid] = 1.0f / fmaxf(sqrtf(s), 1e-12f);
  }
  __syncthreads();
  #pragma unroll
  for (int it = 0; it < 4; ++it) {
    int cid = it * 256 + tid;
    int p = cid >> 4, g = cid & 15;
    int r = p0 + p;
    int sc = (g & ~7) | ((g & 7) ^ (r & 7));
    float inv = sInv[p];
    unsigned pack[4];
    #pragma unroll
    for (int e = 0; e < 8; ++e) {
      float v = sT[p][sc * 8 + e] * inv;
      if ((e & 1) == 0) pack[e >> 1] = (unsigned)f2bf(v);
      else              pack[e >> 1] |= ((unsigned)f2bf(v)) << 16;
    }
    u32x4 o; o.x = pack[0]; o.y = pack[1]; o.z = pack[2]; o.w = pack[3];
    *reinterpret_cast<u32x4*>(out + (size_t)r * CC + g * 8) = o;
  }
}

// ---- kernel 2: pixel-dot GEMM D[s] = Pn[b] . Tn[b*2+s]^T, output in 48x48-block layout ----
__global__ __launch_bounds__(512) void k_pixdot(const u16* __restrict__ PnT, const u16* __restrict__ TnT,
                                                u16* __restrict__ D, int b) {
  __shared__ u16 sA[128 * 128];        // 32 KB = 2048 16B slots
  __shared__ u16 sB[256 * 128];        // 64 KB = 4096 16B slots
  const int nt = blockIdx.x, mt = blockIdx.y, s = blockIdx.z;
  const int tid = threadIdx.x, lane = tid & 63, wid = tid >> 6;
  const int wm = wid >> 2, wn = wid & 3;
  const int r15 = lane & 15, g16 = lane >> 4;

  const u16* Ab = PnT + (size_t)b * NPIX * CC + (size_t)mt * 128 * CC;
  const u16* Bb = TnT + (size_t)(b * 2 + s) * NPIX * CC + (size_t)nt * 256 * CC;
  u16* Dset = D + (size_t)s * SETSZ;

  #pragma unroll
  for (int i = 0; i < 4; ++i) {
    int sl = i * 512 + tid;
    __builtin_amdgcn_global_load_lds(
      (const __attribute__((address_space(1))) unsigned*)(Ab + (size_t)(sl >> 4) * CC + (sl & 15) * 8),
      (__attribute__((address_space(3))) unsigned*)&sA[sl * 8], 16, 0, 0);
  }
  #pragma unroll
  for (int i = 0; i < 8; ++i) {
    int sl = i * 512 + tid;
    __builtin_amdgcn_global_load_lds(
      (const __attribute__((address_space(1))) unsigned*)(Bb + (size_t)(sl >> 4) * CC + (sl & 15) * 8),
      (__attribute__((address_space(3))) unsigned*)&sB[sl * 8], 16, 0, 0);
  }

  f32x4 acc[4][4];
  const f32x4 z4 = {0.f, 0.f, 0.f, 0.f};
  #pragma unroll
  for (int i = 0; i < 4; ++i)
    #pragma unroll
    for (int j = 0; j < 4; ++j) acc[i][j] = z4;

  asm volatile("s_waitcnt vmcnt(0)" ::: "memory");
  __builtin_amdgcn_s_barrier();

  const int arow0 = wm * 64 + r15;
  const int brow0 = wn * 64 + r15;
  #pragma unroll
  for (int ks = 0; ks < 4; ++ks) {
    const int c = ks * 4 + g16;
    short8 af[4], bfv[4];
    #pragma unroll
    for (int mi = 0; mi < 4; ++mi) {
      int row = arow0 + mi * 16;
      af[mi] = *reinterpret_cast<const short8*>(
        &sA[row * 128 + (c >> 3) * 64 + (((c & 7) ^ (row & 7)) * 8)]);
    }
    #pragma unroll
    for (int ni = 0; ni < 4; ++ni) {
      int row = brow0 + ni * 16;
      bfv[ni] = *reinterpret_cast<const short8*>(
        &sB[row * 128 + (c >> 3) * 64 + (((c & 7) ^ (row & 7)) * 8)]);
    }
    __builtin_amdgcn_s_setprio(1);
    #pragma unroll
    for (int mi = 0; mi < 4; ++mi)
      #pragma unroll
      for (int ni = 0; ni < 4; ++ni)
        acc[mi][ni] = __builtin_amdgcn_mfma_f32_16x16x32_bf16(af[mi], bfv[ni], acc[mi][ni], 0, 0, 0);
    __builtin_amdgcn_s_setprio(0);
  }

  const int m0 = mt * 128 + wm * 64, n0 = nt * 256 + wn * 64;
  #pragma unroll
  for (int mi = 0; mi < 4; ++mi)
    #pragma unroll
    for (int ni = 0; ni < 4; ++ni)
      #pragma unroll
      for (int rg = 0; rg < 4; ++rg) {
        int row = m0 + mi * 16 + g16 * 4 + rg;
        int col = n0 + ni * 16 + r15;
        int rb = row / 48, u = row - rb * 48;
        int cb = col / 48, v = col - cb * 48;
        Dset[(size_t)(rb * 48 + cb) * HW2 + u * 48 + v] = f2bf(acc[mi][ni][rg]);
      }
}

// ---- kernel 2.5: in-place diagonal 3-sum per 48x48 block: hD[x][n] = D[x][n]+D[x+1][n+1]+D[x+2][n+2] ----
// Valid region x,n <= 45 (rest garbage, never read). 4 blocks per workgroup via LDS snapshot.
__global__ __launch_bounds__(256) void k_hsum(u16* __restrict__ D) {
  const int wg = blockIdx.x;           // 1152 wgs x 4 blocks = 4608 = 2 sets * 2304
  const int tid = threadIdx.x;
  __shared__ u16 sB[4 * 2304 + 16];
  u16* gbase = D + (size_t)wg * 4 * 2304;

  #pragma unroll
  for (int i = 0; i < 5; ++i) {
    int sl = i * 256 + tid;
    if (sl < 1152)
      __builtin_amdgcn_global_load_lds(
        (const __attribute__((address_space(1))) unsigned*)(gbase + sl * 8),
        (__attribute__((address_space(3))) unsigned*)&sB[sl * 8], 16, 0, 0);
  }
  asm volatile("s_waitcnt vmcnt(0)" ::: "memory");
  __builtin_amdgcn_s_barrier();

  #pragma unroll
  for (int i = 0; i < 5; ++i) {        // 4 blocks * 46 rows * 6 chunks = 1104 tasks
    int t = i * 256 + tid;
    if (t < 1104) {
      int blk = t / 276, rem = t - blk * 276;
      int x = rem / 6, ch = rem - x * 6;
      int base = blk * 2304 + x * 48 + ch * 8;
      short8 a  = *reinterpret_cast<const short8*>(&sB[base]);
      short8 b0 = *reinterpret_cast<const short8*>(&sB[base + 48]);
      short8 b1 = *reinterpret_cast<const short8*>(&sB[base + 56]);
      short8 c0 = *reinterpret_cast<const short8*>(&sB[base + 96]);
      short8 c1 = *reinterpret_cast<const short8*>(&sB[base + 104]);
      short8 s1 = __builtin_shufflevector(b0, b1, 1, 2, 3, 4, 5, 6, 7, 8);
      short8 s2 = __builtin_shufflevector(c0, c1, 2, 3, 4, 5, 6, 7, 8, 9);
      unsigned pack[4];
      #pragma unroll
      for (int e = 0; e < 8; ++e) {
        float f = b2f((u16)a[e]) + b2f((u16)s1[e]) + b2f((u16)s2[e]);
        if ((e & 1) == 0) pack[e >> 1] = (unsigned)f2bf(f);
        else              pack[e >> 1] |= ((unsigned)f2bf(f)) << 16;
      }
      u32x4 o; o.x = pack[0]; o.y = pack[1]; o.z = pack[2]; o.w = pack[3];
      *reinterpret_cast<u32x4*>(gbase + base) = o;   // in-place (LDS snapshot read)
    }
  }
}

// ---- kernel 3: blocked stencil, now 3 taps (di only) on hsummed blocks ----
__global__ __launch_bounds__(256) void k_stencil(const u16* __restrict__ D,
                                                 float* __restrict__ pval, u16* __restrict__ pidx,
                                                 int b) {
  const int qy = blockIdx.x;        // 0..45
  const int nyc = blockIdx.y;       // 0..7  (ny = nyc*6 + j, j<6, ny<46)
  const int tid = threadIdx.x, lane = tid & 63, w = tid >> 6;

  __shared__ u16 sM[2][7040];

  float best[12]; int bidx[12];
  #pragma unroll
  for (int s = 0; s < 12; ++s) { best[s] = -3.0e38f; bidx[s] = 0x7fffffff; }
  const int qx0 = w * 12;

  auto stage = [&](int buf, int kc, int ny) {
    const u16* Dset = D + (size_t)kc * SETSZ;
    #pragma unroll
    for (int i = 0; i < 3; ++i) {
      int sl = i * 256 + tid;
      int di = sl >= 576 ? 2 : (sl >= 288 ? 1 : 0);
      int off = sl - di * 288;
      const u16* src = Dset + (size_t)((qy + di) * 48 + (ny + di)) * HW2 + off * 8;
      __builtin_amdgcn_global_load_lds((const __attribute__((address_space(1))) unsigned*)src,
        (__attribute__((address_space(3))) unsigned*)&sM[buf][sl * 8], 16, 0, 0);
    }
    if (tid < 96) {
      int sl = 768 + tid;
      const u16* src = Dset + (size_t)((qy + 2) * 48 + (ny + 2)) * HW2 + (sl - 576) * 8;
      __builtin_amdgcn_global_load_lds((const __attribute__((address_space(1))) unsigned*)src,
        (__attribute__((address_space(3))) unsigned*)&sM[buf][sl * 8], 16, 0, 0);
    }
  };

  stage(0, 0, nyc * 6);
  asm volatile("s_waitcnt vmcnt(0)" ::: "memory");
  __builtin_amdgcn_s_barrier();

  for (int it = 0; it < 12; ++it) {
    const int buf = it & 1;
    const int kc = it / 6, j = it - kc * 6;
    const int ny = nyc * 6 + j;
    if (it + 1 < 12) {
      int kc1 = (it + 1) / 6, ny1 = nyc * 6 + (it + 1) - kc1 * 6;
      if (ny1 < NHW) stage(buf ^ 1, kc1, ny1);
    }
    if (ny < NHW) {
      #pragma unroll
      for (int s = 0; s < 12; ++s) {
        int qx = qx0 + s;
        float sc = b2f(sM[buf][qx * 48 + lane])
                 + b2f(sM[buf][HW2 + qx * 48 + lane])
                 + b2f(sM[buf][2 * HW2 + qx * 48 + lane]);
        int n = kc * NQ + ny * NHW + lane;
        bool take = (lane < NHW) && (qx < NHW) &&
                    ((sc > best[s]) || (sc == best[s] && n < bidx[s]));
        best[s] = take ? sc : best[s];
        bidx[s] = take ? n : bidx[s];
      }
    }
    asm volatile("s_waitcnt vmcnt(0)" ::: "memory");
    __builtin_amdgcn_s_barrier();
  }

  #pragma unroll
  for (int s = 0; s < 12; ++s) {
    float bv = best[s]; int bi = bidx[s];
    #pragma unroll
    for (int off = 1; off < 64; off <<= 1) {
      float ov = __shfl_xor(bv, off, 64);
      int   oi = __shfl_xor(bi, off, 64);
      bool take = (ov > bv) || (ov == bv && oi < bi);
      bv = take ? ov : bv; bi = take ? oi : bi;
    }
    if (lane == 0) {
      size_t o = ((size_t)(b * NHW + qy) * 48 + (qx0 + s)) * 8 + nyc;
      pval[o] = bv;
      pidx[o] = (u16)(bi & 0xffff);
    }
  }
}

// ---- kernel 4: wave-per-query reduce of 8 ny-chunk partials + raw-patch MSE ----
__global__ __launch_bounds__(256) void k_red(const float* __restrict__ pval, const u16* __restrict__ pidx,
                                             const float* __restrict__ pred, const float* __restrict__ targ,
                                             float* __restrict__ msep) {
  int gw = (blockIdx.x * 256 + threadIdx.x) >> 6;
  int lane = threadIdx.x & 63;
  if (gw >= BATCH * NQ) return;
  int b = gw >= NQ ? 1 : 0;
  int q = gw - b * NQ;
  int qy = q / NHW, qx = q - qy * NHW;

  size_t base = ((size_t)(b * NHW + qy) * 48 + qx) * 8;
  float bv = -3.0e38f; int bi = 0x7fffffff;
  if (lane < 8) { bv = pval[base + lane]; bi = pidx[base + lane]; }
  #pragma unroll
  for (int off = 1; off < 64; off <<= 1) {
    float ov = __shfl_xor(bv, off, 64);
    int   oi = __shfl_xor(bi, off, 64);
    bool take = (ov > bv) || (ov == bv && oi < bi);
    bv = take ? ov : bv; bi = take ? oi : bi;
  }
  int kc = bi >= NQ ? 1 : 0;
  int ns = bi - kc * NQ;
  ns = ns < NQ ? ns : NQ - 1;
  int ny = ns / NHW, nx = ns - ny * NHW;

  const float* P = pred + (size_t)b * CC * HW2;
  const float* T = targ + (size_t)(b * 2 + kc) * CC * HW2;
  float ssum = 0.f;
  for (int i = lane; i < CC * 9; i += 64) {
    int c = i / 9, sp = i - 9 * c;
    int di = sp / 3, dj = sp - 3 * di;
    float d = P[(size_t)c * HW2 + (qy + di) * WW + qx + dj]
            - T[(size_t)c * HW2 + (ny + di) * WW + nx + dj];
    ssum += d * d;
  }
  #pragma unroll
  for (int off = 1; off < 64; off <<= 1) ssum += __shfl_xor(ssum, off, 64);
  if (lane == 0) msep[gw] = ssum;
}

// ---- kernel 5: final deterministic reduction ----
__global__ void k_final(const float* __restrict__ msep, float* __restrict__ out) {
  int t = threadIdx.x;
  float s = 0.f;
  for (int i = t; i < BATCH * NQ; i += 256) s += msep[i];
  __shared__ float red[256];
  red[t] = s; __syncthreads();
  for (int st = 128; st > 0; st >>= 1) { if (t < st) red[t] += red[t + st]; __syncthreads(); }
  if (t == 0) out[0] = red[0] * (1.0f / 4875264.0f);   // 2*2116*128*9
}

extern "C" void kernel_launch(void* const* d_in, const int* in_sizes, int n_in,
                              void* d_out, int out_size, void* d_ws, size_t ws_size,
                              hipStream_t stream) {
  const float* pred = (const float*)d_in[0];
  const float* targ = (const float*)d_in[1];
  char* ws = (char*)d_ws;

  size_t offP  = 0;
  size_t offT  = offP  + (size_t)2 * NPIX * CC * 2;        // PnT: 1,179,648
  size_t offD  = offT  + (size_t)4 * NPIX * CC * 2;        // TnT: 2,359,296
  size_t offPv = offD  + (size_t)2 * SETSZ * 2 + 256;      // D (2 sets)+pad: 21,233,920
  size_t offPi = offPv + (size_t)2 * NHW * 48 * 8 * 4;     // pval: 141,312
  size_t offM  = offPi + (size_t)2 * NHW * 48 * 8 * 2;     // pidx: 70,656

  u16*   PnT  = (u16*)(ws + offP);
  u16*   TnT  = (u16*)(ws + offT);
  u16*   Dbuf = (u16*)(ws + offD);
  float* pval = (float*)(ws + offPv);
  u16*   pidx = (u16*)(ws + offPi);
  float* msep = (float*)(ws + offM);                       // total ~25 MB

  k_norm<<<dim3(36, 6), 256, 0, stream>>>(pred, targ, PnT, TnT);
  k_pixdot<<<dim3(9, 18, 2), 512, 0, stream>>>(PnT, TnT, Dbuf, 0);
  k_hsum<<<dim3(1152), 256, 0, stream>>>(Dbuf);
  k_stencil<<<dim3(NHW, 8), 256, 0, stream>>>(Dbuf, pval, pidx, 0);
  k_pixdot<<<dim3(9, 18, 2), 512, 0, stream>>>(PnT, TnT, Dbuf, 1);
  k_hsum<<<dim3(1152), 256, 0, stream>>>(Dbuf);
  k_stencil<<<dim3(NHW, 8), 256, 0, stream>>>(Dbuf, pval, pidx, 1);
  k_red<<<dim3((BATCH * NQ + 3) / 4), 256, 0, stream>>>(pval, pidx, pred, targ, msep);
  k_final<<<1, 256, 0, stream>>>(msep, (float*)d_out);
}

// Round 11
// 103.981 us; speedup vs baseline: 1.2780x; 1.2780x over previous
//
#include <hip/hip_runtime.h>
#include <hip/hip_bf16.h>

typedef unsigned short u16;
typedef __attribute__((ext_vector_type(8))) short short8;
typedef __attribute__((ext_vector_type(4))) float f32x4;
typedef __attribute__((ext_vector_type(4))) unsigned int u32x4;

#define CC    128
#define WW    48
#define HW2   2304      // 48*48
#define NHW   46
#define NQ    2116      // 46*46
#define NPIX  2304      // pixels per image
#define DSTRIDE ((size_t)NPIX * NPIX + 64)   // D elems per set, +tail pad for 64-lane overrun
#define BATCH 2

__device__ __forceinline__ u16 f2bf(float f) {
  union { float f; unsigned u; } x; x.f = f;
  unsigned r = (x.u + 0x7fffu + ((x.u >> 16) & 1u)) >> 16;
  return (u16)r;
}
__device__ __forceinline__ float b2f(u16 v) {
  union { unsigned u; float f; } x; x.u = ((unsigned)v) << 16;
  return x.f;
}

// ---- kernel 1: per-pixel normalize + transpose to [pix][128c] bf16, chunk-swizzled ----
__global__ __launch_bounds__(256) void k_norm(const float* __restrict__ pred,
                                              const float* __restrict__ targ,
                                              u16* __restrict__ PnT, u16* __restrict__ TnT) {
  const int img = blockIdx.y;          // 0..5 : 0-1 pred, 2-5 target
  const int p0  = blockIdx.x * 64;     // 36 blocks of 64 pixels
  const int tid = threadIdx.x;
  const float* src = img < 2 ? pred + (size_t)img * CC * HW2
                             : targ + (size_t)(img - 2) * CC * HW2;
  u16* out = img < 2 ? PnT + (size_t)img * NPIX * CC
                     : TnT + (size_t)(img - 2) * NPIX * CC;

  __shared__ float sT[64][129];
  __shared__ float sInv[64];

  #pragma unroll
  for (int it = 0; it < 32; ++it) {
    int idx = it * 256 + tid;
    int c = idx >> 6, p = idx & 63;
    sT[p][c] = src[(size_t)c * HW2 + p0 + p];
  }
  __syncthreads();
  if (tid < 64) {
    float s = 0.f;
    for (int c = 0; c < CC; ++c) { float v = sT[tid][c]; s += v * v; }
    sInv[tid] = 1.0f / fmaxf(sqrtf(s), 1e-12f);
  }
  __syncthreads();
  #pragma unroll
  for (int it = 0; it < 4; ++it) {
    int cid = it * 256 + tid;
    int p = cid >> 4, g = cid & 15;
    int r = p0 + p;
    int sc = (g & ~7) | ((g & 7) ^ (r & 7));
    float inv = sInv[p];
    unsigned pack[4];
    #pragma unroll
    for (int e = 0; e < 8; ++e) {
      float v = sT[p][sc * 8 + e] * inv;
      if ((e & 1) == 0) pack[e >> 1] = (unsigned)f2bf(v);
      else              pack[e >> 1] |= ((unsigned)f2bf(v)) << 16;
    }
    u32x4 o; o.x = pack[0]; o.y = pack[1]; o.z = pack[2]; o.w = pack[3];
    *reinterpret_cast<u32x4*>(out + (size_t)r * CC + g * 8) = o;
  }
}

// ---- kernel 2: pixel-dot GEMM  D[s] = Pn[b] . Tn[b*2+s]^T  (2304x2304, K=128) ----
__global__ __launch_bounds__(512) void k_pixdot(const u16* __restrict__ PnT, const u16* __restrict__ TnT,
                                                u16* __restrict__ D, int b) {
  __shared__ u16 sA[128 * 128];        // 32 KB = 2048 16B slots
  __shared__ u16 sB[256 * 128];        // 64 KB = 4096 16B slots
  const int nt = blockIdx.x, mt = blockIdx.y, s = blockIdx.z;
  const int tid = threadIdx.x, lane = tid & 63, wid = tid >> 6;
  const int wm = wid >> 2, wn = wid & 3;
  const int r15 = lane & 15, g16 = lane >> 4;

  const u16* Ab = PnT + (size_t)b * NPIX * CC + (size_t)mt * 128 * CC;
  const u16* Bb = TnT + (size_t)(b * 2 + s) * NPIX * CC + (size_t)nt * 256 * CC;
  u16* Dset = D + (size_t)s * DSTRIDE;

  #pragma unroll
  for (int i = 0; i < 4; ++i) {
    int sl = i * 512 + tid;
    __builtin_amdgcn_global_load_lds(
      (const __attribute__((address_space(1))) unsigned*)(Ab + (size_t)(sl >> 4) * CC + (sl & 15) * 8),
      (__attribute__((address_space(3))) unsigned*)&sA[sl * 8], 16, 0, 0);
  }
  #pragma unroll
  for (int i = 0; i < 8; ++i) {
    int sl = i * 512 + tid;
    __builtin_amdgcn_global_load_lds(
      (const __attribute__((address_space(1))) unsigned*)(Bb + (size_t)(sl >> 4) * CC + (sl & 15) * 8),
      (__attribute__((address_space(3))) unsigned*)&sB[sl * 8], 16, 0, 0);
  }

  f32x4 acc[4][4];
  const f32x4 z4 = {0.f, 0.f, 0.f, 0.f};
  #pragma unroll
  for (int i = 0; i < 4; ++i)
    #pragma unroll
    for (int j = 0; j < 4; ++j) acc[i][j] = z4;

  asm volatile("s_waitcnt vmcnt(0)" ::: "memory");
  __builtin_amdgcn_s_barrier();

  const int arow0 = wm * 64 + r15;
  const int brow0 = wn * 64 + r15;
  #pragma unroll
  for (int ks = 0; ks < 4; ++ks) {
    const int c = ks * 4 + g16;
    short8 af[4], bfv[4];
    #pragma unroll
    for (int mi = 0; mi < 4; ++mi) {
      int row = arow0 + mi * 16;
      af[mi] = *reinterpret_cast<const short8*>(
        &sA[row * 128 + (c >> 3) * 64 + (((c & 7) ^ (row & 7)) * 8)]);
    }
    #pragma unroll
    for (int ni = 0; ni < 4; ++ni) {
      int row = brow0 + ni * 16;
      bfv[ni] = *reinterpret_cast<const short8*>(
        &sB[row * 128 + (c >> 3) * 64 + (((c & 7) ^ (row & 7)) * 8)]);
    }
    __builtin_amdgcn_s_setprio(1);
    #pragma unroll
    for (int mi = 0; mi < 4; ++mi)
      #pragma unroll
      for (int ni = 0; ni < 4; ++ni)
        acc[mi][ni] = __builtin_amdgcn_mfma_f32_16x16x32_bf16(af[mi], bfv[ni], acc[mi][ni], 0, 0, 0);
    __builtin_amdgcn_s_setprio(0);
  }

  const int m0 = mt * 128 + wm * 64, n0 = nt * 256 + wn * 64;
  #pragma unroll
  for (int mi = 0; mi < 4; ++mi)
    #pragma unroll
    for (int ni = 0; ni < 4; ++ni)
      #pragma unroll
      for (int rg = 0; rg < 4; ++rg) {
        int row = m0 + mi * 16 + g16 * 4 + rg;
        int col = n0 + ni * 16 + r15;
        Dset[(size_t)row * NPIX + col] = f2bf(acc[mi][ni][rg]);
      }
}

// ---- kernel 3: 9-tap stencil + argmax + raw-patch MSE, XCD-chunked q assignment ----
__global__ __launch_bounds__(256) void k_stencil(const u16* __restrict__ D,
                                                 const float* __restrict__ pred,
                                                 const float* __restrict__ targ,
                                                 float* __restrict__ msep, int b) {
  // bijective XCD swizzle over 2116 blocks (q=264, r=4): xcd gets a contiguous q-range,
  // so each XCD's L2 holds only its qy-window's D rows (~3.5 MB < 4 MB).
  const int bid = blockIdx.x;
  const int xcd = bid & 7, pos = bid >> 3;
  const int q = (xcd < 4 ? xcd * 265 : 1060 + (xcd - 4) * 264) + pos;

  const int tid = threadIdx.x, lane = tid & 63, wid = tid >> 6;
  const int kc = wid >> 1, half = wid & 1;     // wave -> (candidate set, ny half)
  const int qy = q / NHW, qx = q - qy * NHW;
  const int qp = qy * WW + qx;

  const u16* Dset = D + (size_t)kc * DSTRIDE;
  const u16* pr[9];
  #pragma unroll
  for (int di = 0; di < 3; ++di)
    #pragma unroll
    for (int dj = 0; dj < 3; ++dj)
      pr[di * 3 + dj] = Dset + (size_t)(qp + di * WW + dj) * NPIX + dj + lane;

  float best = -3.0e38f; int bidx = 0x7fffffff;
  const bool valid = lane < NHW;
  const int ny0 = half * 23;
  for (int ny = ny0; ny < ny0 + 23; ++ny) {
    float sc = 0.f;
    #pragma unroll
    for (int di = 0; di < 3; ++di)
      #pragma unroll
      for (int dj = 0; dj < 3; ++dj)
        sc += b2f(pr[di * 3 + dj][(ny + di) * WW]);
    int n = kc * NQ + ny * NHW + lane;
    bool take = valid && (sc > best || (sc == best && n < bidx));
    best = take ? sc : best;
    bidx = take ? n : bidx;
  }
  #pragma unroll
  for (int off = 1; off < 64; off <<= 1) {
    float ov = __shfl_xor(best, off, 64);
    int   oi = __shfl_xor(bidx, off, 64);
    bool take = (ov > best) || (ov == best && oi < bidx);
    best = take ? ov : best;
    bidx = take ? oi : bidx;
  }

  __shared__ float sv[4]; __shared__ int si[4];
  __shared__ float red[256];
  if (lane == 0) { sv[wid] = best; si[wid] = bidx; }
  __syncthreads();
  float fb = sv[0]; int fi = si[0];
  #pragma unroll
  for (int wv = 1; wv < 4; ++wv) {
    bool take = (sv[wv] > fb) || (sv[wv] == fb && si[wv] < fi);
    fb = take ? sv[wv] : fb;
    fi = take ? si[wv] : fi;
  }

  // raw-patch MSE against the selected target patch
  int nkc = fi >= NQ ? 1 : 0;
  int ns = fi - nkc * NQ;
  int ny = ns / NHW, nx = ns - ny * NHW;
  const float* P = pred + (size_t)b * CC * HW2;
  const float* T = targ + (size_t)(b * 2 + nkc) * CC * HW2;
  float ssum = 0.f;
  for (int i = tid; i < CC * 9; i += 256) {
    int c = i / 9, sp = i - 9 * c;
    int di = sp / 3, dj = sp - 3 * di;
    float d = P[(size_t)c * HW2 + (qy + di) * WW + qx + dj]
            - T[(size_t)c * HW2 + (ny + di) * WW + nx + dj];
    ssum += d * d;
  }
  red[tid] = ssum; __syncthreads();
  for (int st = 128; st > 0; st >>= 1) { if (tid < st) red[tid] += red[tid + st]; __syncthreads(); }
  if (tid == 0) msep[b * NQ + q] = red[0];
}

// ---- kernel 4: final deterministic reduction ----
__global__ void k_final(const float* __restrict__ msep, float* __restrict__ out) {
  int t = threadIdx.x;
  float s = 0.f;
  for (int i = t; i < BATCH * NQ; i += 256) s += msep[i];
  __shared__ float red[256];
  red[t] = s; __syncthreads();
  for (int st = 128; st > 0; st >>= 1) { if (t < st) red[t] += red[t + st]; __syncthreads(); }
  if (t == 0) out[0] = red[0] * (1.0f / 4875264.0f);   // 2*2116*128*9
}

extern "C" void kernel_launch(void* const* d_in, const int* in_sizes, int n_in,
                              void* d_out, int out_size, void* d_ws, size_t ws_size,
                              hipStream_t stream) {
  const float* pred = (const float*)d_in[0];
  const float* targ = (const float*)d_in[1];
  char* ws = (char*)d_ws;

  size_t offP = 0;
  size_t offT = offP + (size_t)2 * NPIX * CC * 2;     // PnT: 1,179,648
  size_t offD = offT + (size_t)4 * NPIX * CC * 2;     // TnT: 2,359,296
  size_t offM = offD + (size_t)2 * DSTRIDE * 2;       // D (2 sets): 21,234,176

  u16*   PnT  = (u16*)(ws + offP);
  u16*   TnT  = (u16*)(ws + offT);
  u16*   Dbuf = (u16*)(ws + offD);
  float* msep = (float*)(ws + offM);                  // total ~24.8 MB

  k_norm<<<dim3(36, 6), 256, 0, stream>>>(pred, targ, PnT, TnT);
  k_pixdot<<<dim3(9, 18, 2), 512, 0, stream>>>(PnT, TnT, Dbuf, 0);
  k_stencil<<<dim3(NQ), 256, 0, stream>>>(Dbuf, pred, targ, msep, 0);
  k_pixdot<<<dim3(9, 18, 2), 512, 0, stream>>>(PnT, TnT, Dbuf, 1);
  k_stencil<<<dim3(NQ), 256, 0, stream>>>(Dbuf, pred, targ, msep, 1);
  k_final<<<1, 256, 0, stream>>>(msep, (float*)d_out);
}

// Round 12
// 92.287 us; speedup vs baseline: 1.4400x; 1.1267x over previous
//
#include <hip/hip_runtime.h>
#include <hip/hip_bf16.h>

typedef unsigned short u16;
typedef __attribute__((ext_vector_type(8))) short short8;
typedef __attribute__((ext_vector_type(4))) float f32x4;
typedef __attribute__((ext_vector_type(4))) unsigned int u32x4;

#define CC    128
#define WW    48
#define HW2   2304      // 48*48
#define NHW   46
#define NQ    2116      // 46*46
#define NPIX  2304      // pixels per image
#define DSTRIDE ((size_t)NPIX * NPIX + 64)   // D elems per set, +tail pad for 64-lane overrun
#define BATCH 2

__device__ __forceinline__ u16 f2bf(float f) {
  union { float f; unsigned u; } x; x.f = f;
  unsigned r = (x.u + 0x7fffu + ((x.u >> 16) & 1u)) >> 16;
  return (u16)r;
}
__device__ __forceinline__ float b2f(u16 v) {
  union { unsigned u; float f; } x; x.u = ((unsigned)v) << 16;
  return x.f;
}

// ---- kernel 1: per-pixel normalize + transpose to [pix][128c] bf16, chunk-swizzled ----
__global__ __launch_bounds__(256) void k_norm(const float* __restrict__ pred,
                                              const float* __restrict__ targ,
                                              u16* __restrict__ PnT, u16* __restrict__ TnT) {
  const int img = blockIdx.y;          // 0..5 : 0-1 pred, 2-5 target
  const int p0  = blockIdx.x * 64;     // 36 blocks of 64 pixels
  const int tid = threadIdx.x;
  const float* src = img < 2 ? pred + (size_t)img * CC * HW2
                             : targ + (size_t)(img - 2) * CC * HW2;
  u16* out = img < 2 ? PnT + (size_t)img * NPIX * CC
                     : TnT + (size_t)(img - 2) * NPIX * CC;

  __shared__ float sT[64][129];
  __shared__ float sInv[64];

  #pragma unroll
  for (int it = 0; it < 32; ++it) {
    int idx = it * 256 + tid;
    int c = idx >> 6, p = idx & 63;
    sT[p][c] = src[(size_t)c * HW2 + p0 + p];
  }
  __syncthreads();
  if (tid < 64) {
    float s = 0.f;
    for (int c = 0; c < CC; ++c) { float v = sT[tid][c]; s += v * v; }
    sInv[tid] = 1.0f / fmaxf(sqrtf(s), 1e-12f);
  }
  __syncthreads();
  #pragma unroll
  for (int it = 0; it < 4; ++it) {
    int cid = it * 256 + tid;
    int p = cid >> 4, g = cid & 15;
    int r = p0 + p;
    int sc = (g & ~7) | ((g & 7) ^ (r & 7));
    float inv = sInv[p];
    unsigned pack[4];
    #pragma unroll
    for (int e = 0; e < 8; ++e) {
      float v = sT[p][sc * 8 + e] * inv;
      if ((e & 1) == 0) pack[e >> 1] = (unsigned)f2bf(v);
      else              pack[e >> 1] |= ((unsigned)f2bf(v)) << 16;
    }
    u32x4 o; o.x = pack[0]; o.y = pack[1]; o.z = pack[2]; o.w = pack[3];
    *reinterpret_cast<u32x4*>(out + (size_t)r * CC + g * 8) = o;
  }
}

// ---- kernel 2: pixel-dot GEMM, all 4 (b,kc) sets in one launch ----
// D[s] = Pn[s>>1] . Tn[s]^T   (TnT image index == set index s)
__global__ __launch_bounds__(512) void k_pixdot(const u16* __restrict__ PnT, const u16* __restrict__ TnT,
                                                u16* __restrict__ D) {
  __shared__ u16 sA[128 * 128];        // 32 KB = 2048 16B slots
  __shared__ u16 sB[256 * 128];        // 64 KB = 4096 16B slots
  const int nt = blockIdx.x, mt = blockIdx.y, s = blockIdx.z;
  const int tid = threadIdx.x, lane = tid & 63, wid = tid >> 6;
  const int wm = wid >> 2, wn = wid & 3;
  const int r15 = lane & 15, g16 = lane >> 4;

  const u16* Ab = PnT + (size_t)(s >> 1) * NPIX * CC + (size_t)mt * 128 * CC;
  const u16* Bb = TnT + (size_t)s * NPIX * CC + (size_t)nt * 256 * CC;
  u16* Dset = D + (size_t)s * DSTRIDE;

  #pragma unroll
  for (int i = 0; i < 4; ++i) {
    int sl = i * 512 + tid;
    __builtin_amdgcn_global_load_lds(
      (const __attribute__((address_space(1))) unsigned*)(Ab + (size_t)(sl >> 4) * CC + (sl & 15) * 8),
      (__attribute__((address_space(3))) unsigned*)&sA[sl * 8], 16, 0, 0);
  }
  #pragma unroll
  for (int i = 0; i < 8; ++i) {
    int sl = i * 512 + tid;
    __builtin_amdgcn_global_load_lds(
      (const __attribute__((address_space(1))) unsigned*)(Bb + (size_t)(sl >> 4) * CC + (sl & 15) * 8),
      (__attribute__((address_space(3))) unsigned*)&sB[sl * 8], 16, 0, 0);
  }

  f32x4 acc[4][4];
  const f32x4 z4 = {0.f, 0.f, 0.f, 0.f};
  #pragma unroll
  for (int i = 0; i < 4; ++i)
    #pragma unroll
    for (int j = 0; j < 4; ++j) acc[i][j] = z4;

  asm volatile("s_waitcnt vmcnt(0)" ::: "memory");
  __builtin_amdgcn_s_barrier();

  const int arow0 = wm * 64 + r15;
  const int brow0 = wn * 64 + r15;
  #pragma unroll
  for (int ks = 0; ks < 4; ++ks) {
    const int c = ks * 4 + g16;
    short8 af[4], bfv[4];
    #pragma unroll
    for (int mi = 0; mi < 4; ++mi) {
      int row = arow0 + mi * 16;
      af[mi] = *reinterpret_cast<const short8*>(
        &sA[row * 128 + (c >> 3) * 64 + (((c & 7) ^ (row & 7)) * 8)]);
    }
    #pragma unroll
    for (int ni = 0; ni < 4; ++ni) {
      int row = brow0 + ni * 16;
      bfv[ni] = *reinterpret_cast<const short8*>(
        &sB[row * 128 + (c >> 3) * 64 + (((c & 7) ^ (row & 7)) * 8)]);
    }
    __builtin_amdgcn_s_setprio(1);
    #pragma unroll
    for (int mi = 0; mi < 4; ++mi)
      #pragma unroll
      for (int ni = 0; ni < 4; ++ni)
        acc[mi][ni] = __builtin_amdgcn_mfma_f32_16x16x32_bf16(af[mi], bfv[ni], acc[mi][ni], 0, 0, 0);
    __builtin_amdgcn_s_setprio(0);
  }

  const int m0 = mt * 128 + wm * 64, n0 = nt * 256 + wn * 64;
  #pragma unroll
  for (int mi = 0; mi < 4; ++mi)
    #pragma unroll
    for (int ni = 0; ni < 4; ++ni)
      #pragma unroll
      for (int rg = 0; rg < 4; ++rg) {
        int row = m0 + mi * 16 + g16 * 4 + rg;
        int col = n0 + ni * 16 + r15;
        Dset[(size_t)row * NPIX + col] = f2bf(acc[mi][ni][rg]);
      }
}

// ---- kernel 3: 9-tap stencil + argmax + raw-patch MSE; 8 waves = 2kc x 4 ny-quarters ----
__global__ __launch_bounds__(512) void k_stencil(const u16* __restrict__ D,
                                                 const float* __restrict__ pred,
                                                 const float* __restrict__ targ,
                                                 float* __restrict__ msep) {
  // b-major halves; within each half, bijective XCD-chunked q (L2 window ~3.5 MB/XCD)
  const int bid = blockIdx.x;
  const int b = bid >= NQ ? 1 : 0;
  const int orig = bid - b * NQ;
  const int xcd = orig & 7, pos = orig >> 3;
  const int q = (xcd < 4 ? xcd * 265 : 1060 + (xcd - 4) * 264) + pos;

  const int tid = threadIdx.x, lane = tid & 63, wid = tid >> 6;
  const int kc = wid >> 2, quarter = wid & 3;  // wave -> (candidate set, ny quarter)
  const int qy = q / NHW, qx = q - qy * NHW;
  const int qp = qy * WW + qx;

  const u16* Dset = D + (size_t)(b * 2 + kc) * DSTRIDE;
  const u16* pr[9];
  #pragma unroll
  for (int di = 0; di < 3; ++di)
    #pragma unroll
    for (int dj = 0; dj < 3; ++dj)
      pr[di * 3 + dj] = Dset + (size_t)(qp + di * WW + dj) * NPIX + dj + lane;

  float best = -3.0e38f; int bidx = 0x7fffffff;
  const bool valid = lane < NHW;
  const int ny0 = quarter * 12;
  for (int i = 0; i < 12; ++i) {
    int ny = ny0 + i;
    if (ny >= NHW) break;
    float sc = 0.f;
    #pragma unroll
    for (int di = 0; di < 3; ++di)
      #pragma unroll
      for (int dj = 0; dj < 3; ++dj)
        sc += b2f(pr[di * 3 + dj][(ny + di) * WW]);
    int n = kc * NQ + ny * NHW + lane;
    bool take = valid && (sc > best || (sc == best && n < bidx));
    best = take ? sc : best;
    bidx = take ? n : bidx;
  }
  #pragma unroll
  for (int off = 1; off < 64; off <<= 1) {
    float ov = __shfl_xor(best, off, 64);
    int   oi = __shfl_xor(bidx, off, 64);
    bool take = (ov > best) || (ov == best && oi < bidx);
    best = take ? ov : best;
    bidx = take ? oi : bidx;
  }

  __shared__ float sv[8]; __shared__ int si[8];
  __shared__ float red[512];
  if (lane == 0) { sv[wid] = best; si[wid] = bidx; }
  __syncthreads();
  float fb = sv[0]; int fi = si[0];
  #pragma unroll
  for (int wv = 1; wv < 8; ++wv) {
    bool take = (sv[wv] > fb) || (sv[wv] == fb && si[wv] < fi);
    fb = take ? sv[wv] : fb;
    fi = take ? si[wv] : fi;
  }

  // raw-patch MSE against the selected target patch
  int nkc = fi >= NQ ? 1 : 0;
  int ns = fi - nkc * NQ;
  int ny = ns / NHW, nx = ns - ny * NHW;
  const float* P = pred + (size_t)b * CC * HW2;
  const float* T = targ + (size_t)(b * 2 + nkc) * CC * HW2;
  float ssum = 0.f;
  for (int i = tid; i < CC * 9; i += 512) {
    int c = i / 9, sp = i - 9 * c;
    int di = sp / 3, dj = sp - 3 * di;
    float d = P[(size_t)c * HW2 + (qy + di) * WW + qx + dj]
            - T[(size_t)c * HW2 + (ny + di) * WW + nx + dj];
    ssum += d * d;
  }
  red[tid] = ssum; __syncthreads();
  for (int st = 256; st > 0; st >>= 1) { if (tid < st) red[tid] += red[tid + st]; __syncthreads(); }
  if (tid == 0) msep[b * NQ + q] = red[0];
}

// ---- kernel 4: final deterministic reduction ----
__global__ void k_final(const float* __restrict__ msep, float* __restrict__ out) {
  int t = threadIdx.x;
  float s = 0.f;
  for (int i = t; i < BATCH * NQ; i += 256) s += msep[i];
  __shared__ float red[256];
  red[t] = s; __syncthreads();
  for (int st = 128; st > 0; st >>= 1) { if (t < st) red[t] += red[t + st]; __syncthreads(); }
  if (t == 0) out[0] = red[0] * (1.0f / 4875264.0f);   // 2*2116*128*9
}

extern "C" void kernel_launch(void* const* d_in, const int* in_sizes, int n_in,
                              void* d_out, int out_size, void* d_ws, size_t ws_size,
                              hipStream_t stream) {
  const float* pred = (const float*)d_in[0];
  const float* targ = (const float*)d_in[1];
  char* ws = (char*)d_ws;

  size_t offP = 0;
  size_t offT = offP + (size_t)2 * NPIX * CC * 2;     // PnT: 1,179,648
  size_t offD = offT + (size_t)4 * NPIX * CC * 2;     // TnT: 2,359,296
  size_t offM = offD + (size_t)4 * DSTRIDE * 2;       // D (4 sets): 42,467,840

  u16*   PnT  = (u16*)(ws + offP);
  u16*   TnT  = (u16*)(ws + offT);
  u16*   Dbuf = (u16*)(ws + offD);
  float* msep = (float*)(ws + offM);                  // total ~46 MB

  k_norm<<<dim3(36, 6), 256, 0, stream>>>(pred, targ, PnT, TnT);
  k_pixdot<<<dim3(9, 18, 4), 512, 0, stream>>>(PnT, TnT, Dbuf);
  k_stencil<<<dim3(BATCH * NQ), 512, 0, stream>>>(Dbuf, pred, targ, msep);
  k_final<<<1, 256, 0, stream>>>(msep, (float*)d_out);
}

// Round 13
// 79.994 us; speedup vs baseline: 1.6613x; 1.1537x over previous
//
#include <hip/hip_runtime.h>
#include <hip/hip_bf16.h>

typedef unsigned short u16;
typedef __attribute__((ext_vector_type(8))) short short8;
typedef __attribute__((ext_vector_type(4))) float f32x4;
typedef __attribute__((ext_vector_type(4))) unsigned int u32x4;

#define CC    128
#define WW    48
#define HW2   2304      // 48*48
#define NHW   46
#define NQ    2116      // 46*46
#define NPIX  2304      // pixels per image
#define DSTRIDE ((size_t)NPIX * NPIX + 64)   // elems per set, +tail pad for vector overrun
#define BATCH 2

__device__ __forceinline__ u16 f2bf(float f) {
  union { float f; unsigned u; } x; x.f = f;
  unsigned r = (x.u + 0x7fffu + ((x.u >> 16) & 1u)) >> 16;
  return (u16)r;
}
__device__ __forceinline__ float b2f(u16 v) {
  union { unsigned u; float f; } x; x.u = ((unsigned)v) << 16;
  return x.f;
}

// ---- kernel 1: per-pixel normalize + transpose to [pix][128c] bf16, chunk-swizzled ----
__global__ __launch_bounds__(256) void k_norm(const float* __restrict__ pred,
                                              const float* __restrict__ targ,
                                              u16* __restrict__ PnT, u16* __restrict__ TnT) {
  const int img = blockIdx.y;          // 0..5 : 0-1 pred, 2-5 target
  const int p0  = blockIdx.x * 64;     // 36 blocks of 64 pixels
  const int tid = threadIdx.x;
  const float* src = img < 2 ? pred + (size_t)img * CC * HW2
                             : targ + (size_t)(img - 2) * CC * HW2;
  u16* out = img < 2 ? PnT + (size_t)img * NPIX * CC
                     : TnT + (size_t)(img - 2) * NPIX * CC;

  __shared__ float sT[64][129];
  __shared__ float sInv[64];

  #pragma unroll
  for (int it = 0; it < 32; ++it) {
    int idx = it * 256 + tid;
    int c = idx >> 6, p = idx & 63;
    sT[p][c] = src[(size_t)c * HW2 + p0 + p];
  }
  __syncthreads();
  if (tid < 64) {
    float s = 0.f;
    for (int c = 0; c < CC; ++c) { float v = sT[tid][c]; s += v * v; }
    sInv[tid] = 1.0f / fmaxf(sqrtf(s), 1e-12f);
  }
  __syncthreads();
  #pragma unroll
  for (int it = 0; it < 4; ++it) {
    int cid = it * 256 + tid;
    int p = cid >> 4, g = cid & 15;
    int r = p0 + p;
    int sc = (g & ~7) | ((g & 7) ^ (r & 7));
    float inv = sInv[p];
    unsigned pack[4];
    #pragma unroll
    for (int e = 0; e < 8; ++e) {
      float v = sT[p][sc * 8 + e] * inv;
      if ((e & 1) == 0) pack[e >> 1] = (unsigned)f2bf(v);
      else              pack[e >> 1] |= ((unsigned)f2bf(v)) << 16;
    }
    u32x4 o; o.x = pack[0]; o.y = pack[1]; o.z = pack[2]; o.w = pack[3];
    *reinterpret_cast<u32x4*>(out + (size_t)r * CC + g * 8) = o;
  }
}

// ---- kernel 2: pixel-dot GEMM, all 4 (b,kc) sets in one launch ----
__global__ __launch_bounds__(512) void k_pixdot(const u16* __restrict__ PnT, const u16* __restrict__ TnT,
                                                u16* __restrict__ D) {
  __shared__ u16 sA[128 * 128];        // 32 KB = 2048 16B slots
  __shared__ u16 sB[256 * 128];        // 64 KB = 4096 16B slots
  const int nt = blockIdx.x, mt = blockIdx.y, s = blockIdx.z;
  const int tid = threadIdx.x, lane = tid & 63, wid = tid >> 6;
  const int wm = wid >> 2, wn = wid & 3;
  const int r15 = lane & 15, g16 = lane >> 4;

  const u16* Ab = PnT + (size_t)(s >> 1) * NPIX * CC + (size_t)mt * 128 * CC;
  const u16* Bb = TnT + (size_t)s * NPIX * CC + (size_t)nt * 256 * CC;
  u16* Dset = D + (size_t)s * DSTRIDE;

  #pragma unroll
  for (int i = 0; i < 4; ++i) {
    int sl = i * 512 + tid;
    __builtin_amdgcn_global_load_lds(
      (const __attribute__((address_space(1))) unsigned*)(Ab + (size_t)(sl >> 4) * CC + (sl & 15) * 8),
      (__attribute__((address_space(3))) unsigned*)&sA[sl * 8], 16, 0, 0);
  }
  #pragma unroll
  for (int i = 0; i < 8; ++i) {
    int sl = i * 512 + tid;
    __builtin_amdgcn_global_load_lds(
      (const __attribute__((address_space(1))) unsigned*)(Bb + (size_t)(sl >> 4) * CC + (sl & 15) * 8),
      (__attribute__((address_space(3))) unsigned*)&sB[sl * 8], 16, 0, 0);
  }

  f32x4 acc[4][4];
  const f32x4 z4 = {0.f, 0.f, 0.f, 0.f};
  #pragma unroll
  for (int i = 0; i < 4; ++i)
    #pragma unroll
    for (int j = 0; j < 4; ++j) acc[i][j] = z4;

  asm volatile("s_waitcnt vmcnt(0)" ::: "memory");
  __builtin_amdgcn_s_barrier();

  const int arow0 = wm * 64 + r15;
  const int brow0 = wn * 64 + r15;
  #pragma unroll
  for (int ks = 0; ks < 4; ++ks) {
    const int c = ks * 4 + g16;
    short8 af[4], bfv[4];
    #pragma unroll
    for (int mi = 0; mi < 4; ++mi) {
      int row = arow0 + mi * 16;
      af[mi] = *reinterpret_cast<const short8*>(
        &sA[row * 128 + (c >> 3) * 64 + (((c & 7) ^ (row & 7)) * 8)]);
    }
    #pragma unroll
    for (int ni = 0; ni < 4; ++ni) {
      int row = brow0 + ni * 16;
      bfv[ni] = *reinterpret_cast<const short8*>(
        &sB[row * 128 + (c >> 3) * 64 + (((c & 7) ^ (row & 7)) * 8)]);
    }
    __builtin_amdgcn_s_setprio(1);
    #pragma unroll
    for (int mi = 0; mi < 4; ++mi)
      #pragma unroll
      for (int ni = 0; ni < 4; ++ni)
        acc[mi][ni] = __builtin_amdgcn_mfma_f32_16x16x32_bf16(af[mi], bfv[ni], acc[mi][ni], 0, 0, 0);
    __builtin_amdgcn_s_setprio(0);
  }

  const int m0 = mt * 128 + wm * 64, n0 = nt * 256 + wn * 64;
  #pragma unroll
  for (int mi = 0; mi < 4; ++mi)
    #pragma unroll
    for (int ni = 0; ni < 4; ++ni)
      #pragma unroll
      for (int rg = 0; rg < 4; ++rg) {
        int row = m0 + mi * 16 + g16 * 4 + rg;
        int col = n0 + ni * 16 + r15;
        Dset[(size_t)row * NPIX + col] = f2bf(acc[mi][ni][rg]);
      }
}

// ---- kernel 2.5: diagonal-3 pass  H[r][c] = D[r][c] + D[r+1][c+1] + D[r+2][c+2] ----
// rows r < 2302 (rows >=2302 never read downstream); XCD-chunked for row reuse in L2.
#define HTASKS (2302 * 288)            // per set: rows x col-chunks of 8
#define HNB    ((4 * HTASKS) / 256)    // 10359 blocks, exact
__global__ __launch_bounds__(256) void k_hsum(const u16* __restrict__ D, u16* __restrict__ H) {
  const int bid = blockIdx.x;
  const int xcd = bid & 7, pos = bid >> 3;
  const int qch = HNB >> 3, rch = HNB & 7;   // 1294, 7
  const int sb = (xcd < rch ? xcd * (qch + 1) : rch * (qch + 1) + (xcd - rch) * qch) + pos;
  const int task = sb * 256 + threadIdx.x;
  const int s = task / HTASKS;
  int rem = task - s * HTASKS;
  const int r = rem / 288, c8 = rem - r * 288;

  const u16* Ds = D + (size_t)s * DSTRIDE + (size_t)r * NPIX + c8 * 8;
  u16* Hs = H + (size_t)s * DSTRIDE + (size_t)r * NPIX + c8 * 8;

  short8 a0 = *reinterpret_cast<const short8*>(Ds);
  short8 b0 = *reinterpret_cast<const short8*>(Ds + NPIX);
  short8 b1 = *reinterpret_cast<const short8*>(Ds + NPIX + 8);
  short8 c0 = *reinterpret_cast<const short8*>(Ds + 2 * NPIX);
  short8 c1 = *reinterpret_cast<const short8*>(Ds + 2 * NPIX + 8);
  short8 s1 = __builtin_shufflevector(b0, b1, 1, 2, 3, 4, 5, 6, 7, 8);
  short8 s2 = __builtin_shufflevector(c0, c1, 2, 3, 4, 5, 6, 7, 8, 9);
  unsigned pack[4];
  #pragma unroll
  for (int e = 0; e < 8; ++e) {
    float f = b2f((u16)a0[e]) + b2f((u16)s1[e]) + b2f((u16)s2[e]);
    if ((e & 1) == 0) pack[e >> 1] = (unsigned)f2bf(f);
    else              pack[e >> 1] |= ((unsigned)f2bf(f)) << 16;
  }
  u32x4 o; o.x = pack[0]; o.y = pack[1]; o.z = pack[2]; o.w = pack[3];
  *reinterpret_cast<u32x4*>(Hs) = o;
}

// ---- kernel 3: 3-tap vectorized stencil + argmax + raw-patch MSE ----
// S(q,n) = H[qp][np] + H[qp+48][np+48] + H[qp+96][np+96]; lane covers 8 nx.
__global__ __launch_bounds__(512) void k_stencil(const u16* __restrict__ H,
                                                 const float* __restrict__ pred,
                                                 const float* __restrict__ targ,
                                                 float* __restrict__ msep) {
  const int bid = blockIdx.x;
  const int b = bid >= NQ ? 1 : 0;
  const int orig = bid - b * NQ;
  const int xcd = orig & 7, pos = orig >> 3;
  const int q = (xcd < 4 ? xcd * 265 : 1060 + (xcd - 4) * 264) + pos;

  const int tid = threadIdx.x, lane = tid & 63, wid = tid >> 6;
  const int qy = q / NHW, qx = q - qy * NHW;
  const int qp = qy * WW + qx;

  float best = -3.0e38f; int bidx = 0x7fffffff;
  #pragma unroll
  for (int it = 0; it < 2; ++it) {             // 552 tasks = kc(2) x ny(46) x cx(6)
    int t = it * 512 + tid;
    if (t < 552) {
      int kc = t / 276; int rem = t - kc * 276;
      int ny = rem / 6, cx = rem - ny * 6;
      const u16* Hs = H + (size_t)(b * 2 + kc) * DSTRIDE;
      int colb = ny * 48 + cx * 8;
      short8 t0 = *reinterpret_cast<const short8*>(Hs + (size_t)qp * NPIX + colb);
      short8 t1 = *reinterpret_cast<const short8*>(Hs + (size_t)(qp + 48) * NPIX + colb + 48);
      short8 t2 = *reinterpret_cast<const short8*>(Hs + (size_t)(qp + 96) * NPIX + colb + 96);
      int nbase = kc * NQ + ny * NHW + cx * 8;
      #pragma unroll
      for (int e = 0; e < 8; ++e) {
        float sc = b2f((u16)t0[e]) + b2f((u16)t1[e]) + b2f((u16)t2[e]);
        int n = nbase + e;
        bool take = (cx * 8 + e < NHW) &&
                    ((sc > best) || (sc == best && n < bidx));
        best = take ? sc : best;
        bidx = take ? n : bidx;
      }
    }
  }
  #pragma unroll
  for (int off = 1; off < 64; off <<= 1) {
    float ov = __shfl_xor(best, off, 64);
    int   oi = __shfl_xor(bidx, off, 64);
    bool take = (ov > best) || (ov == best && oi < bidx);
    best = take ? ov : best;
    bidx = take ? oi : bidx;
  }

  __shared__ float sv[8]; __shared__ int si[8];
  __shared__ float red[512];
  if (lane == 0) { sv[wid] = best; si[wid] = bidx; }
  __syncthreads();
  float fb = sv[0]; int fi = si[0];
  #pragma unroll
  for (int wv = 1; wv < 8; ++wv) {
    bool take = (sv[wv] > fb) || (sv[wv] == fb && si[wv] < fi);
    fb = take ? sv[wv] : fb;
    fi = take ? si[wv] : fi;
  }

  // raw-patch MSE against the selected target patch
  int nkc = fi >= NQ ? 1 : 0;
  int ns = fi - nkc * NQ;
  int ny = ns / NHW, nx = ns - ny * NHW;
  const float* P = pred + (size_t)b * CC * HW2;
  const float* T = targ + (size_t)(b * 2 + nkc) * CC * HW2;
  float ssum = 0.f;
  for (int i = tid; i < CC * 9; i += 512) {
    int c = i / 9, sp = i - 9 * c;
    int di = sp / 3, dj = sp - 3 * di;
    float d = P[(size_t)c * HW2 + (qy + di) * WW + qx + dj]
            - T[(size_t)c * HW2 + (ny + di) * WW + nx + dj];
    ssum += d * d;
  }
  red[tid] = ssum; __syncthreads();
  for (int st = 256; st > 0; st >>= 1) { if (tid < st) red[tid] += red[tid + st]; __syncthreads(); }
  if (tid == 0) msep[b * NQ + q] = red[0];
}

// ---- kernel 4: final deterministic reduction ----
__global__ void k_final(const float* __restrict__ msep, float* __restrict__ out) {
  int t = threadIdx.x;
  float s = 0.f;
  for (int i = t; i < BATCH * NQ; i += 256) s += msep[i];
  __shared__ float red[256];
  red[t] = s; __syncthreads();
  for (int st = 128; st > 0; st >>= 1) { if (t < st) red[t] += red[t + st]; __syncthreads(); }
  if (t == 0) out[0] = red[0] * (1.0f / 4875264.0f);   // 2*2116*128*9
}

extern "C" void kernel_launch(void* const* d_in, const int* in_sizes, int n_in,
                              void* d_out, int out_size, void* d_ws, size_t ws_size,
                              hipStream_t stream) {
  const float* pred = (const float*)d_in[0];
  const float* targ = (const float*)d_in[1];
  char* ws = (char*)d_ws;

  size_t offP = 0;
  size_t offT = offP + (size_t)2 * NPIX * CC * 2;     // PnT: 1,179,648
  size_t offD = offT + (size_t)4 * NPIX * CC * 2;     // TnT: 2,359,296
  size_t offH = offD + (size_t)4 * DSTRIDE * 2;       // D (4 sets): 42,467,840
  size_t offM = offH + (size_t)4 * DSTRIDE * 2;       // H (4 sets): 42,467,840

  u16*   PnT  = (u16*)(ws + offP);
  u16*   TnT  = (u16*)(ws + offT);
  u16*   Dbuf = (u16*)(ws + offD);
  u16*   Hbuf = (u16*)(ws + offH);
  float* msep = (float*)(ws + offM);                  // total ~89 MB

  k_norm<<<dim3(36, 6), 256, 0, stream>>>(pred, targ, PnT, TnT);
  k_pixdot<<<dim3(9, 18, 4), 512, 0, stream>>>(PnT, TnT, Dbuf);
  k_hsum<<<dim3(HNB), 256, 0, stream>>>(Dbuf, Hbuf);
  k_stencil<<<dim3(BATCH * NQ), 512, 0, stream>>>(Hbuf, pred, targ, msep);
  k_final<<<1, 256, 0, stream>>>(msep, (float*)d_out);
}

// Round 15
// 77.504 us; speedup vs baseline: 1.7146x; 1.0321x over previous
//
#include <hip/hip_runtime.h>
#include <hip/hip_bf16.h>

typedef unsigned short u16;
typedef __attribute__((ext_vector_type(8))) short short8;
typedef __attribute__((ext_vector_type(4))) float f32x4;
typedef __attribute__((ext_vector_type(4))) unsigned int u32x4;

#define CC    128
#define WW    48
#define HW2   2304      // 48*48
#define NHW   46
#define NQ    2116      // 46*46
#define NPIX  2304      // pixels per image
#define DSTRIDE ((size_t)NPIX * NPIX + 64)   // elems per set, +tail pad for vector overrun
#define BATCH 2
#define MT    126       // H rows emitted per tile
#define NTC   254       // H cols emitted per tile

__device__ __forceinline__ u16 f2bf(float f) {
  union { float f; unsigned u; } x; x.f = f;
  unsigned r = (x.u + 0x7fffu + ((x.u >> 16) & 1u)) >> 16;
  return (u16)r;
}
__device__ __forceinline__ float b2f(u16 v) {
  union { unsigned u; float f; } x; x.u = ((unsigned)v) << 16;
  return x.f;
}

// ---- kernel 1: per-pixel normalize + transpose to [pix][128c] bf16, chunk-swizzled ----
__global__ __launch_bounds__(256) void k_norm(const float* __restrict__ pred,
                                              const float* __restrict__ targ,
                                              u16* __restrict__ PnT, u16* __restrict__ TnT) {
  const int img = blockIdx.y;          // 0..5 : 0-1 pred, 2-5 target
  const int p0  = blockIdx.x * 64;     // 36 blocks of 64 pixels
  const int tid = threadIdx.x;
  const float* src = img < 2 ? pred + (size_t)img * CC * HW2
                             : targ + (size_t)(img - 2) * CC * HW2;
  u16* out = img < 2 ? PnT + (size_t)img * NPIX * CC
                     : TnT + (size_t)(img - 2) * NPIX * CC;

  __shared__ float sT[64][129];
  __shared__ float sInv[64];

  #pragma unroll
  for (int it = 0; it < 32; ++it) {
    int idx = it * 256 + tid;
    int c = idx >> 6, p = idx & 63;
    sT[p][c] = src[(size_t)c * HW2 + p0 + p];
  }
  __syncthreads();
  if (tid < 64) {
    float s = 0.f;
    for (int c = 0; c < CC; ++c) { float v = sT[tid][c]; s += v * v; }
    sInv[tid] = 1.0f / fmaxf(sqrtf(s), 1e-12f);
  }
  __syncthreads();
  #pragma unroll
  for (int it = 0; it < 4; ++it) {
    int cid = it * 256 + tid;
    int p = cid >> 4, g = cid & 15;
    int r = p0 + p;
    int sc = (g & ~7) | ((g & 7) ^ (r & 7));
    float inv = sInv[p];
    unsigned pack[4];
    #pragma unroll
    for (int e = 0; e < 8; ++e) {
      float v = sT[p][sc * 8 + e] * inv;
      if ((e & 1) == 0) pack[e >> 1] = (unsigned)f2bf(v);
      else              pack[e >> 1] |= ((unsigned)f2bf(v)) << 16;
    }
    u32x4 o; o.x = pack[0]; o.y = pack[1]; o.z = pack[2]; o.w = pack[3];
    *reinterpret_cast<u32x4*>(out + (size_t)r * CC + g * 8) = o;
  }
}

// ---- kernel 2: pixel-dot GEMM + in-LDS diagonal-3 epilogue -> H directly ----
// Block computes D tile rows m0..m0+127 x cols n0..n0+255 (K=128, MFMA), spills it
// to LDS as bf16, then emits H[r][c] = D[r][c]+D[r+1][c+1]+D[r+2][c+2] for the
// interior 126x254 region. Grid strides 126/254 so tiles partition H exactly.
// NOTE: un-swizzle XOR must use the GLOBAL row (m0/n0 not multiples of 8).
__global__ __launch_bounds__(512) void k_pixdotH(const u16* __restrict__ PnT, const u16* __restrict__ TnT,
                                                 u16* __restrict__ H) {
  __shared__ u16 buf[49152];           // 96 KB: sA 32 KB | sB 64 KB ; reused as Dt 64 KB
  u16* sA = buf;
  u16* sB = buf + 16384;
  const int nt = blockIdx.x, mt = blockIdx.y, s = blockIdx.z;
  const int tid = threadIdx.x, lane = tid & 63, wid = tid >> 6;
  const int wm = wid >> 2, wn = wid & 3;
  const int r15 = lane & 15, g16 = lane >> 4;
  const int m0 = mt * MT, n0 = nt * NTC;

  const u16* Ab = PnT + (size_t)(s >> 1) * NPIX * CC;
  const u16* Bb = TnT + (size_t)s * NPIX * CC;
  u16* Hs = H + (size_t)s * DSTRIDE;

  #pragma unroll
  for (int i = 0; i < 4; ++i) {
    int sl = i * 512 + tid;
    int row = m0 + (sl >> 4); row = row < 2303 ? row : 2303;   // clamp at edge
    __builtin_amdgcn_global_load_lds(
      (const __attribute__((address_space(1))) unsigned*)(Ab + (size_t)row * CC + (sl & 15) * 8),
      (__attribute__((address_space(3))) unsigned*)&sA[sl * 8], 16, 0, 0);
  }
  #pragma unroll
  for (int i = 0; i < 8; ++i) {
    int sl = i * 512 + tid;
    int row = n0 + (sl >> 4); row = row < 2303 ? row : 2303;
    __builtin_amdgcn_global_load_lds(
      (const __attribute__((address_space(1))) unsigned*)(Bb + (size_t)row * CC + (sl & 15) * 8),
      (__attribute__((address_space(3))) unsigned*)&sB[sl * 8], 16, 0, 0);
  }

  f32x4 acc[4][4];
  const f32x4 z4 = {0.f, 0.f, 0.f, 0.f};
  #pragma unroll
  for (int i = 0; i < 4; ++i)
    #pragma unroll
    for (int j = 0; j < 4; ++j) acc[i][j] = z4;

  asm volatile("s_waitcnt vmcnt(0)" ::: "memory");
  __builtin_amdgcn_s_barrier();

  const int arow0 = wm * 64 + r15;
  const int brow0 = wn * 64 + r15;
  #pragma unroll
  for (int ks = 0; ks < 4; ++ks) {
    const int c = ks * 4 + g16;
    short8 af[4], bfv[4];
    #pragma unroll
    for (int mi = 0; mi < 4; ++mi) {
      int row = arow0 + mi * 16;
      int gr = m0 + row;                       // global row drives the un-swizzle
      af[mi] = *reinterpret_cast<const short8*>(
        &sA[row * 128 + (c >> 3) * 64 + (((c & 7) ^ (gr & 7)) * 8)]);
    }
    #pragma unroll
    for (int ni = 0; ni < 4; ++ni) {
      int row = brow0 + ni * 16;
      int gr = n0 + row;
      bfv[ni] = *reinterpret_cast<const short8*>(
        &sB[row * 128 + (c >> 3) * 64 + (((c & 7) ^ (gr & 7)) * 8)]);
    }
    __builtin_amdgcn_s_setprio(1);
    #pragma unroll
    for (int mi = 0; mi < 4; ++mi)
      #pragma unroll
      for (int ni = 0; ni < 4; ++ni)
        acc[mi][ni] = __builtin_amdgcn_mfma_f32_16x16x32_bf16(af[mi], bfv[ni], acc[mi][ni], 0, 0, 0);
    __builtin_amdgcn_s_setprio(0);
  }

  // ---- spill D tile to LDS (bf16), aliasing the staging buffers ----
  __syncthreads();                     // all MFMA operand reads done
  u16* Dt = buf;                       // [128][256]
  #pragma unroll
  for (int mi = 0; mi < 4; ++mi)
    #pragma unroll
    for (int ni = 0; ni < 4; ++ni) {
      int col = wn * 64 + ni * 16 + r15;
      #pragma unroll
      for (int rg = 0; rg < 4; ++rg) {
        int row = wm * 64 + mi * 16 + g16 * 4 + rg;
        Dt[row * 256 + col] = f2bf(acc[mi][ni][rg]);
      }
    }
  __syncthreads();

  // ---- emit H = diagonal-3 of Dt, interior 126x254, clipped at image edge ----
  for (int t = tid; t < 4032; t += 512) {        // 126 rows x 32 col-chunks
    int rr = t >> 5, c8 = t & 31;
    int grow = m0 + rr;
    if (grow >= 2302) continue;
    int lcol = c8 * 8;
    int lim = 254 - lcol;
    int glim = 2302 - (n0 + lcol);
    lim = lim < glim ? lim : glim;
    if (lim <= 0) continue;
    int base = rr * 256 + lcol;
    short8 a0 = *reinterpret_cast<const short8*>(&Dt[base]);
    short8 b0 = *reinterpret_cast<const short8*>(&Dt[base + 256]);
    short8 b1 = *reinterpret_cast<const short8*>(&Dt[base + 264]);
    short8 c0 = *reinterpret_cast<const short8*>(&Dt[base + 512]);
    short8 c1 = *reinterpret_cast<const short8*>(&Dt[base + 520]);
    short8 s1v = __builtin_shufflevector(b0, b1, 1, 2, 3, 4, 5, 6, 7, 8);
    short8 s2v = __builtin_shufflevector(c0, c1, 2, 3, 4, 5, 6, 7, 8, 9);
    unsigned pack[4];
    #pragma unroll
    for (int e = 0; e < 8; ++e) {
      float f = b2f((u16)a0[e]) + b2f((u16)s1v[e]) + b2f((u16)s2v[e]);
      if ((e & 1) == 0) pack[e >> 1] = (unsigned)f2bf(f);
      else              pack[e >> 1] |= ((unsigned)f2bf(f)) << 16;
    }
    u16* dst = Hs + (size_t)grow * NPIX + n0 + lcol;
    int nd = lim >= 8 ? 4 : ((lim + 1) >> 1);    // lim is 6 at c8==31, else even
    #pragma unroll
    for (int d = 0; d < 4; ++d)
      if (d < nd) *reinterpret_cast<unsigned*>(dst + 2 * d) = pack[d];
  }
}

// ---- kernel 3: 3-tap vectorized stencil + argmax + raw-patch MSE ----
__global__ __launch_bounds__(512) void k_stencil(const u16* __restrict__ H,
                                                 const float* __restrict__ pred,
                                                 const float* __restrict__ targ,
                                                 float* __restrict__ msep) {
  const int bid = blockIdx.x;
  const int b = bid >= NQ ? 1 : 0;
  const int orig = bid - b * NQ;
  const int xcd = orig & 7, pos = orig >> 3;
  const int q = (xcd < 4 ? xcd * 265 : 1060 + (xcd - 4) * 264) + pos;

  const int tid = threadIdx.x, lane = tid & 63, wid = tid >> 6;
  const int qy = q / NHW, qx = q - qy * NHW;
  const int qp = qy * WW + qx;

  float best = -3.0e38f; int bidx = 0x7fffffff;
  #pragma unroll
  for (int it = 0; it < 2; ++it) {             // 552 tasks = kc(2) x ny(46) x cx(6)
    int t = it * 512 + tid;
    if (t < 552) {
      int kc = t / 276; int rem = t - kc * 276;
      int ny = rem / 6, cx = rem - ny * 6;
      const u16* Hs = H + (size_t)(b * 2 + kc) * DSTRIDE;
      int colb = ny * 48 + cx * 8;
      short8 t0 = *reinterpret_cast<const short8*>(Hs + (size_t)qp * NPIX + colb);
      short8 t1 = *reinterpret_cast<const short8*>(Hs + (size_t)(qp + 48) * NPIX + colb + 48);
      short8 t2 = *reinterpret_cast<const short8*>(Hs + (size_t)(qp + 96) * NPIX + colb + 96);
      int nbase = kc * NQ + ny * NHW + cx * 8;
      #pragma unroll
      for (int e = 0; e < 8; ++e) {
        float sc = b2f((u16)t0[e]) + b2f((u16)t1[e]) + b2f((u16)t2[e]);
        int n = nbase + e;
        bool take = (cx * 8 + e < NHW) &&
                    ((sc > best) || (sc == best && n < bidx));
        best = take ? sc : best;
        bidx = take ? n : bidx;
      }
    }
  }
  #pragma unroll
  for (int off = 1; off < 64; off <<= 1) {
    float ov = __shfl_xor(best, off, 64);
    int   oi = __shfl_xor(bidx, off, 64);
    bool take = (ov > best) || (ov == best && oi < bidx);
    best = take ? ov : best;
    bidx = take ? oi : bidx;
  }

  __shared__ float sv[8]; __shared__ int si[8];
  __shared__ float red[512];
  if (lane == 0) { sv[wid] = best; si[wid] = bidx; }
  __syncthreads();
  float fb = sv[0]; int fi = si[0];
  #pragma unroll
  for (int wv = 1; wv < 8; ++wv) {
    bool take = (sv[wv] > fb) || (sv[wv] == fb && si[wv] < fi);
    fb = take ? sv[wv] : fb;
    fi = take ? si[wv] : fi;
  }

  // raw-patch MSE against the selected target patch
  int nkc = fi >= NQ ? 1 : 0;
  int ns = fi - nkc * NQ;
  int ny = ns / NHW, nx = ns - ny * NHW;
  const float* P = pred + (size_t)b * CC * HW2;
  const float* T = targ + (size_t)(b * 2 + nkc) * CC * HW2;
  float ssum = 0.f;
  for (int i = tid; i < CC * 9; i += 512) {
    int c = i / 9, sp = i - 9 * c;
    int di = sp / 3, dj = sp - 3 * di;
    float d = P[(size_t)c * HW2 + (qy + di) * WW + qx + dj]
            - T[(size_t)c * HW2 + (ny + di) * WW + nx + dj];
    ssum += d * d;
  }
  red[tid] = ssum; __syncthreads();
  for (int st = 256; st > 0; st >>= 1) { if (tid < st) red[tid] += red[tid + st]; __syncthreads(); }
  if (tid == 0) msep[b * NQ + q] = red[0];
}

// ---- kernel 4: final deterministic reduction ----
__global__ void k_final(const float* __restrict__ msep, float* __restrict__ out) {
  int t = threadIdx.x;
  float s = 0.f;
  for (int i = t; i < BATCH * NQ; i += 256) s += msep[i];
  __shared__ float red[256];
  red[t] = s; __syncthreads();
  for (int st = 128; st > 0; st >>= 1) { if (t < st) red[t] += red[t + st]; __syncthreads(); }
  if (t == 0) out[0] = red[0] * (1.0f / 4875264.0f);   // 2*2116*128*9
}

extern "C" void kernel_launch(void* const* d_in, const int* in_sizes, int n_in,
                              void* d_out, int out_size, void* d_ws, size_t ws_size,
                              hipStream_t stream) {
  const float* pred = (const float*)d_in[0];
  const float* targ = (const float*)d_in[1];
  char* ws = (char*)d_ws;

  size_t offP = 0;
  size_t offT = offP + (size_t)2 * NPIX * CC * 2;     // PnT: 1,179,648
  size_t offH = offT + (size_t)4 * NPIX * CC * 2;     // TnT: 2,359,296
  size_t offM = offH + (size_t)4 * DSTRIDE * 2;       // H (4 sets): 42,467,840

  u16*   PnT  = (u16*)(ws + offP);
  u16*   TnT  = (u16*)(ws + offT);
  u16*   Hbuf = (u16*)(ws + offH);
  float* msep = (float*)(ws + offM);                  // total ~46 MB

  k_norm<<<dim3(36, 6), 256, 0, stream>>>(pred, targ, PnT, TnT);
  k_pixdotH<<<dim3(10, 19, 4), 512, 0, stream>>>(PnT, TnT, Hbuf);
  k_stencil<<<dim3(BATCH * NQ), 512, 0, stream>>>(Hbuf, pred, targ, msep);
  k_final<<<1, 256, 0, stream>>>(msep, (float*)d_out);
}

// Round 16
// 72.602 us; speedup vs baseline: 1.8304x; 1.0675x over previous
//
#include <hip/hip_runtime.h>
#include <hip/hip_bf16.h>

typedef unsigned short u16;
typedef __attribute__((ext_vector_type(8))) short short8;
typedef __attribute__((ext_vector_type(4))) float f32x4;
typedef __attribute__((ext_vector_type(4))) unsigned int u32x4;

#define CC    128
#define WW    48
#define HW2   2304      // 48*48
#define NHW   46
#define NQ    2116      // 46*46
#define NPIX  2304      // pixels per image
#define DSTRIDE ((size_t)NPIX * NPIX + 64)   // elems per set, +tail pad for vector overrun
#define BATCH 2
#define MT    126       // H rows emitted per tile
#define NTC   190       // H cols emitted per tile
#define DTS   200       // Dt LDS row stride (u16), 16B-aligned rows, conflict-reduced

__device__ __forceinline__ u16 f2bf(float f) {
  union { float f; unsigned u; } x; x.f = f;
  unsigned r = (x.u + 0x7fffu + ((x.u >> 16) & 1u)) >> 16;
  return (u16)r;
}
__device__ __forceinline__ float b2f(u16 v) {
  union { unsigned u; float f; } x; x.u = ((unsigned)v) << 16;
  return x.f;
}

// ---- kernel 1: per-pixel normalize + transpose to [pix][128c] bf16, chunk-swizzled ----
__global__ __launch_bounds__(256) void k_norm(const float* __restrict__ pred,
                                              const float* __restrict__ targ,
                                              u16* __restrict__ PnT, u16* __restrict__ TnT) {
  const int img = blockIdx.y;          // 0..5 : 0-1 pred, 2-5 target
  const int p0  = blockIdx.x * 64;     // 36 blocks of 64 pixels
  const int tid = threadIdx.x;
  const float* src = img < 2 ? pred + (size_t)img * CC * HW2
                             : targ + (size_t)(img - 2) * CC * HW2;
  u16* out = img < 2 ? PnT + (size_t)img * NPIX * CC
                     : TnT + (size_t)(img - 2) * NPIX * CC;

  __shared__ float sT[64][129];
  __shared__ float sInv[64];

  #pragma unroll
  for (int it = 0; it < 32; ++it) {
    int idx = it * 256 + tid;
    int c = idx >> 6, p = idx & 63;
    sT[p][c] = src[(size_t)c * HW2 + p0 + p];
  }
  __syncthreads();
  if (tid < 64) {
    float s = 0.f;
    for (int c = 0; c < CC; ++c) { float v = sT[tid][c]; s += v * v; }
    sInv[tid] = 1.0f / fmaxf(sqrtf(s), 1e-12f);
  }
  __syncthreads();
  #pragma unroll
  for (int it = 0; it < 4; ++it) {
    int cid = it * 256 + tid;
    int p = cid >> 4, g = cid & 15;
    int r = p0 + p;
    int sc = (g & ~7) | ((g & 7) ^ (r & 7));
    float inv = sInv[p];
    unsigned pack[4];
    #pragma unroll
    for (int e = 0; e < 8; ++e) {
      float v = sT[p][sc * 8 + e] * inv;
      if ((e & 1) == 0) pack[e >> 1] = (unsigned)f2bf(v);
      else              pack[e >> 1] |= ((unsigned)f2bf(v)) << 16;
    }
    u32x4 o; o.x = pack[0]; o.y = pack[1]; o.z = pack[2]; o.w = pack[3];
    *reinterpret_cast<u32x4*>(out + (size_t)r * CC + g * 8) = o;
  }
}

// ---- kernel 2: pixel-dot GEMM (128x192) + in-LDS diagonal-3 epilogue -> H ----
// 80 KB LDS (sA 32 + sB 48), Dt (50 KB) aliases it -> 2 blocks/CU.
// Un-swizzle XOR uses GLOBAL row (tile origins not multiples of 8).
__global__ __launch_bounds__(512, 2) void k_pixdotH(const u16* __restrict__ PnT, const u16* __restrict__ TnT,
                                                    u16* __restrict__ H) {
  __shared__ u16 buf[40960];           // 80 KB
  u16* sA = buf;                       // 128 rows x 128 K  (2048 slots)
  u16* sB = buf + 16384;               // 192 rows x 128 K  (3072 slots)
  const int nt = blockIdx.x, mt = blockIdx.y, s = blockIdx.z;
  const int tid = threadIdx.x, lane = tid & 63, wid = tid >> 6;
  const int wm = wid >> 2, wn = wid & 3;
  const int r15 = lane & 15, g16 = lane >> 4;
  const int m0 = mt * MT, n0 = nt * NTC;

  const u16* Ab = PnT + (size_t)(s >> 1) * NPIX * CC;
  const u16* Bb = TnT + (size_t)s * NPIX * CC;
  u16* Hs = H + (size_t)s * DSTRIDE;

  #pragma unroll
  for (int i = 0; i < 4; ++i) {        // A: 2048 slots
    int sl = i * 512 + tid;
    int row = m0 + (sl >> 4); row = row < 2303 ? row : 2303;
    __builtin_amdgcn_global_load_lds(
      (const __attribute__((address_space(1))) unsigned*)(Ab + (size_t)row * CC + (sl & 15) * 8),
      (__attribute__((address_space(3))) unsigned*)&sA[sl * 8], 16, 0, 0);
  }
  #pragma unroll
  for (int i = 0; i < 6; ++i) {        // B: 3072 slots
    int sl = i * 512 + tid;
    int row = n0 + (sl >> 4); row = row < 2303 ? row : 2303;
    __builtin_amdgcn_global_load_lds(
      (const __attribute__((address_space(1))) unsigned*)(Bb + (size_t)row * CC + (sl & 15) * 8),
      (__attribute__((address_space(3))) unsigned*)&sB[sl * 8], 16, 0, 0);
  }

  f32x4 acc[4][3];
  const f32x4 z4 = {0.f, 0.f, 0.f, 0.f};
  #pragma unroll
  for (int i = 0; i < 4; ++i)
    #pragma unroll
    for (int j = 0; j < 3; ++j) acc[i][j] = z4;

  asm volatile("s_waitcnt vmcnt(0)" ::: "memory");
  __builtin_amdgcn_s_barrier();

  const int arow0 = wm * 64 + r15;
  const int brow0 = wn * 48 + r15;
  #pragma unroll
  for (int ks = 0; ks < 4; ++ks) {
    const int c = ks * 4 + g16;
    short8 af[4], bfv[3];
    #pragma unroll
    for (int mi = 0; mi < 4; ++mi) {
      int row = arow0 + mi * 16;
      int gr = m0 + row;
      af[mi] = *reinterpret_cast<const short8*>(
        &sA[row * 128 + (c >> 3) * 64 + (((c & 7) ^ (gr & 7)) * 8)]);
    }
    #pragma unroll
    for (int ni = 0; ni < 3; ++ni) {
      int row = brow0 + ni * 16;
      int gr = n0 + row;
      bfv[ni] = *reinterpret_cast<const short8*>(
        &sB[row * 128 + (c >> 3) * 64 + (((c & 7) ^ (gr & 7)) * 8)]);
    }
    __builtin_amdgcn_s_setprio(1);
    #pragma unroll
    for (int mi = 0; mi < 4; ++mi)
      #pragma unroll
      for (int ni = 0; ni < 3; ++ni)
        acc[mi][ni] = __builtin_amdgcn_mfma_f32_16x16x32_bf16(af[mi], bfv[ni], acc[mi][ni], 0, 0, 0);
    __builtin_amdgcn_s_setprio(0);
  }

  // ---- spill D tile to LDS (bf16), aliasing the staging buffers ----
  __syncthreads();                     // all MFMA operand reads done
  u16* Dt = buf;                       // [128][DTS=200]
  #pragma unroll
  for (int mi = 0; mi < 4; ++mi)
    #pragma unroll
    for (int ni = 0; ni < 3; ++ni) {
      int col = wn * 48 + ni * 16 + r15;
      #pragma unroll
      for (int rg = 0; rg < 4; ++rg) {
        int row = wm * 64 + mi * 16 + g16 * 4 + rg;
        Dt[row * DTS + col] = f2bf(acc[mi][ni][rg]);
      }
    }
  __syncthreads();

  // ---- emit H = diagonal-3 of Dt, interior 126x190, clipped at image edge ----
  for (int t = tid; t < 126 * 24; t += 512) {    // 126 rows x 24 col-chunks
    int rr = t / 24, c8 = t - rr * 24;
    int grow = m0 + rr;
    if (grow >= 2302) continue;
    int lcol = c8 * 8;
    int lim = NTC - lcol;
    int glim = 2302 - (n0 + lcol);
    lim = lim < glim ? lim : glim;
    if (lim <= 0) continue;
    int base = rr * DTS + lcol;
    short8 a0 = *reinterpret_cast<const short8*>(&Dt[base]);
    short8 b0 = *reinterpret_cast<const short8*>(&Dt[base + DTS]);
    short8 b1 = *reinterpret_cast<const short8*>(&Dt[base + DTS + 8]);
    short8 c0 = *reinterpret_cast<const short8*>(&Dt[base + 2 * DTS]);
    short8 c1 = *reinterpret_cast<const short8*>(&Dt[base + 2 * DTS + 8]);
    short8 s1v = __builtin_shufflevector(b0, b1, 1, 2, 3, 4, 5, 6, 7, 8);
    short8 s2v = __builtin_shufflevector(c0, c1, 2, 3, 4, 5, 6, 7, 8, 9);
    unsigned pack[4];
    #pragma unroll
    for (int e = 0; e < 8; ++e) {
      float f = b2f((u16)a0[e]) + b2f((u16)s1v[e]) + b2f((u16)s2v[e]);
      if ((e & 1) == 0) pack[e >> 1] = (unsigned)f2bf(f);
      else              pack[e >> 1] |= ((unsigned)f2bf(f)) << 16;
    }
    u16* dst = Hs + (size_t)grow * NPIX + n0 + lcol;
    int nd = lim >= 8 ? 4 : (lim >> 1);          // lim even by construction
    #pragma unroll
    for (int d = 0; d < 4; ++d)
      if (d < nd) *reinterpret_cast<unsigned*>(dst + 2 * d) = pack[d];
  }
}

// ---- kernel 3: 3-tap vectorized stencil + argmax + raw-patch MSE ----
__global__ __launch_bounds__(512) void k_stencil(const u16* __restrict__ H,
                                                 const float* __restrict__ pred,
                                                 const float* __restrict__ targ,
                                                 float* __restrict__ msep) {
  const int bid = blockIdx.x;
  const int b = bid >= NQ ? 1 : 0;
  const int orig = bid - b * NQ;
  const int xcd = orig & 7, pos = orig >> 3;
  const int q = (xcd < 4 ? xcd * 265 : 1060 + (xcd - 4) * 264) + pos;

  const int tid = threadIdx.x, lane = tid & 63, wid = tid >> 6;
  const int qy = q / NHW, qx = q - qy * NHW;
  const int qp = qy * WW + qx;

  float best = -3.0e38f; int bidx = 0x7fffffff;
  #pragma unroll
  for (int it = 0; it < 2; ++it) {             // 552 tasks = kc(2) x ny(46) x cx(6)
    int t = it * 512 + tid;
    if (t < 552) {
      int kc = t / 276; int rem = t - kc * 276;
      int ny = rem / 6, cx = rem - ny * 6;
      const u16* Hs = H + (size_t)(b * 2 + kc) * DSTRIDE;
      int colb = ny * 48 + cx * 8;
      short8 t0 = *reinterpret_cast<const short8*>(Hs + (size_t)qp * NPIX + colb);
      short8 t1 = *reinterpret_cast<const short8*>(Hs + (size_t)(qp + 48) * NPIX + colb + 48);
      short8 t2 = *reinterpret_cast<const short8*>(Hs + (size_t)(qp + 96) * NPIX + colb + 96);
      int nbase = kc * NQ + ny * NHW + cx * 8;
      #pragma unroll
      for (int e = 0; e < 8; ++e) {
        float sc = b2f((u16)t0[e]) + b2f((u16)t1[e]) + b2f((u16)t2[e]);
        int n = nbase + e;
        bool take = (cx * 8 + e < NHW) &&
                    ((sc > best) || (sc == best && n < bidx));
        best = take ? sc : best;
        bidx = take ? n : bidx;
      }
    }
  }
  #pragma unroll
  for (int off = 1; off < 64; off <<= 1) {
    float ov = __shfl_xor(best, off, 64);
    int   oi = __shfl_xor(bidx, off, 64);
    bool take = (ov > best) || (ov == best && oi < bidx);
    best = take ? ov : best;
    bidx = take ? oi : bidx;
  }

  __shared__ float sv[8]; __shared__ int si[8];
  __shared__ float rsum[8];
  if (lane == 0) { sv[wid] = best; si[wid] = bidx; }
  __syncthreads();
  float fb = sv[0]; int fi = si[0];
  #pragma unroll
  for (int wv = 1; wv < 8; ++wv) {
    bool take = (sv[wv] > fb) || (sv[wv] == fb && si[wv] < fi);
    fb = take ? sv[wv] : fb;
    fi = take ? si[wv] : fi;
  }

  // raw-patch MSE against the selected target patch
  int nkc = fi >= NQ ? 1 : 0;
  int ns = fi - nkc * NQ;
  int ny = ns / NHW, nx = ns - ny * NHW;
  const float* P = pred + (size_t)b * CC * HW2;
  const float* T = targ + (size_t)(b * 2 + nkc) * CC * HW2;
  float ssum = 0.f;
  for (int i = tid; i < CC * 9; i += 512) {
    int c = i / 9, sp = i - 9 * c;
    int di = sp / 3, dj = sp - 3 * di;
    float d = P[(size_t)c * HW2 + (qy + di) * WW + qx + dj]
            - T[(size_t)c * HW2 + (ny + di) * WW + nx + dj];
    ssum += d * d;
  }
  #pragma unroll
  for (int off = 1; off < 64; off <<= 1) ssum += __shfl_xor(ssum, off, 64);
  if (lane == 0) rsum[wid] = ssum;
  __syncthreads();
  if (tid == 0) {
    float t = 0.f;
    #pragma unroll
    for (int wv = 0; wv < 8; ++wv) t += rsum[wv];
    msep[b * NQ + q] = t;
  }
}

// ---- kernel 4: final deterministic reduction ----
__global__ void k_final(const float* __restrict__ msep, float* __restrict__ out) {
  int t = threadIdx.x;
  float s = 0.f;
  for (int i = t; i < BATCH * NQ; i += 256) s += msep[i];
  __shared__ float red[256];
  red[t] = s; __syncthreads();
  for (int st = 128; st > 0; st >>= 1) { if (t < st) red[t] += red[t + st]; __syncthreads(); }
  if (t == 0) out[0] = red[0] * (1.0f / 4875264.0f);   // 2*2116*128*9
}

extern "C" void kernel_launch(void* const* d_in, const int* in_sizes, int n_in,
                              void* d_out, int out_size, void* d_ws, size_t ws_size,
                              hipStream_t stream) {
  const float* pred = (const float*)d_in[0];
  const float* targ = (const float*)d_in[1];
  char* ws = (char*)d_ws;

  size_t offP = 0;
  size_t offT = offP + (size_t)2 * NPIX * CC * 2;     // PnT: 1,179,648
  size_t offH = offT + (size_t)4 * NPIX * CC * 2;     // TnT: 2,359,296
  size_t offM = offH + (size_t)4 * DSTRIDE * 2;       // H (4 sets): 42,467,840

  u16*   PnT  = (u16*)(ws + offP);
  u16*   TnT  = (u16*)(ws + offT);
  u16*   Hbuf = (u16*)(ws + offH);
  float* msep = (float*)(ws + offM);                  // total ~46 MB

  k_norm<<<dim3(36, 6), 256, 0, stream>>>(pred, targ, PnT, TnT);
  k_pixdotH<<<dim3(13, 19, 4), 512, 0, stream>>>(PnT, TnT, Hbuf);
  k_stencil<<<dim3(BATCH * NQ), 512, 0, stream>>>(Hbuf, pred, targ, msep);
  k_final<<<1, 256, 0, stream>>>(msep, (float*)d_out);
}

// Round 17
// 70.243 us; speedup vs baseline: 1.8919x; 1.0336x over previous
//
#include <hip/hip_runtime.h>
#include <hip/hip_bf16.h>

typedef unsigned short u16;
typedef __attribute__((ext_vector_type(8))) short short8;
typedef _Float16 half8 __attribute__((ext_vector_type(8)));
typedef __attribute__((ext_vector_type(4))) float f32x4;
typedef __attribute__((ext_vector_type(4))) unsigned int u32x4;

#define CC    128
#define WW    48
#define HW2   2304      // 48*48
#define NHW   46
#define NQ    2116      // 46*46
#define NPIX  2304      // pixels per image
#define DSTRIDE ((size_t)NPIX * NPIX + 64)   // elems per set, +tail pad for vector overrun
#define BATCH 2
#define MT    126       // H rows emitted per tile
#define NTC   190       // H cols emitted per tile
#define DTS   200       // Dt LDS row stride (u16 units)

__device__ __forceinline__ u16 f2bf(float f) {
  union { float f; unsigned u; } x; x.f = f;
  unsigned r = (x.u + 0x7fffu + ((x.u >> 16) & 1u)) >> 16;
  return (u16)r;
}

// ---- kernel 1: per-pixel normalize + transpose to [pix][128c] bf16, chunk-swizzled ----
__global__ __launch_bounds__(256) void k_norm(const float* __restrict__ pred,
                                              const float* __restrict__ targ,
                                              u16* __restrict__ PnT, u16* __restrict__ TnT) {
  const int img = blockIdx.y;          // 0..5 : 0-1 pred, 2-5 target
  const int p0  = blockIdx.x * 64;     // 36 blocks of 64 pixels
  const int tid = threadIdx.x;
  const float* src = img < 2 ? pred + (size_t)img * CC * HW2
                             : targ + (size_t)(img - 2) * CC * HW2;
  u16* out = img < 2 ? PnT + (size_t)img * NPIX * CC
                     : TnT + (size_t)(img - 2) * NPIX * CC;

  __shared__ float sT[64][129];
  __shared__ float sInv[64];

  #pragma unroll
  for (int it = 0; it < 32; ++it) {
    int idx = it * 256 + tid;
    int c = idx >> 6, p = idx & 63;
    sT[p][c] = src[(size_t)c * HW2 + p0 + p];
  }
  __syncthreads();
  if (tid < 64) {
    float s = 0.f;
    for (int c = 0; c < CC; ++c) { float v = sT[tid][c]; s += v * v; }
    sInv[tid] = 1.0f / fmaxf(sqrtf(s), 1e-12f);
  }
  __syncthreads();
  #pragma unroll
  for (int it = 0; it < 4; ++it) {
    int cid = it * 256 + tid;
    int p = cid >> 4, g = cid & 15;
    int r = p0 + p;
    int sc = (g & ~7) | ((g & 7) ^ (r & 7));
    float inv = sInv[p];
    unsigned pack[4];
    #pragma unroll
    for (int e = 0; e < 8; ++e) {
      float v = sT[p][sc * 8 + e] * inv;
      if ((e & 1) == 0) pack[e >> 1] = (unsigned)f2bf(v);
      else              pack[e >> 1] |= ((unsigned)f2bf(v)) << 16;
    }
    u32x4 o; o.x = pack[0]; o.y = pack[1]; o.z = pack[2]; o.w = pack[3];
    *reinterpret_cast<u32x4*>(out + (size_t)r * CC + g * 8) = o;
  }
}

// ---- kernel 2: pixel-dot GEMM (128x192) + in-LDS diagonal-3 epilogue -> H (f16) ----
__global__ __launch_bounds__(512, 2) void k_pixdotH(const u16* __restrict__ PnT, const u16* __restrict__ TnT,
                                                    u16* __restrict__ H) {
  __shared__ u16 buf[40960];           // 80 KB
  u16* sA = buf;                       // 128 rows x 128 K  (2048 slots)
  u16* sB = buf + 16384;               // 192 rows x 128 K  (3072 slots)
  const int nt = blockIdx.x, mt = blockIdx.y, s = blockIdx.z;
  const int tid = threadIdx.x, lane = tid & 63, wid = tid >> 6;
  const int wm = wid >> 2, wn = wid & 3;
  const int r15 = lane & 15, g16 = lane >> 4;
  const int m0 = mt * MT, n0 = nt * NTC;

  const u16* Ab = PnT + (size_t)(s >> 1) * NPIX * CC;
  const u16* Bb = TnT + (size_t)s * NPIX * CC;
  u16* Hs = H + (size_t)s * DSTRIDE;

  #pragma unroll
  for (int i = 0; i < 4; ++i) {        // A: 2048 slots
    int sl = i * 512 + tid;
    int row = m0 + (sl >> 4); row = row < 2303 ? row : 2303;
    __builtin_amdgcn_global_load_lds(
      (const __attribute__((address_space(1))) unsigned*)(Ab + (size_t)row * CC + (sl & 15) * 8),
      (__attribute__((address_space(3))) unsigned*)&sA[sl * 8], 16, 0, 0);
  }
  #pragma unroll
  for (int i = 0; i < 6; ++i) {        // B: 3072 slots
    int sl = i * 512 + tid;
    int row = n0 + (sl >> 4); row = row < 2303 ? row : 2303;
    __builtin_amdgcn_global_load_lds(
      (const __attribute__((address_space(1))) unsigned*)(Bb + (size_t)row * CC + (sl & 15) * 8),
      (__attribute__((address_space(3))) unsigned*)&sB[sl * 8], 16, 0, 0);
  }

  f32x4 acc[4][3];
  const f32x4 z4 = {0.f, 0.f, 0.f, 0.f};
  #pragma unroll
  for (int i = 0; i < 4; ++i)
    #pragma unroll
    for (int j = 0; j < 3; ++j) acc[i][j] = z4;

  asm volatile("s_waitcnt vmcnt(0)" ::: "memory");
  __builtin_amdgcn_s_barrier();

  const int arow0 = wm * 64 + r15;
  const int brow0 = wn * 48 + r15;
  #pragma unroll
  for (int ks = 0; ks < 4; ++ks) {
    const int c = ks * 4 + g16;
    short8 af[4], bfv[3];
    #pragma unroll
    for (int mi = 0; mi < 4; ++mi) {
      int row = arow0 + mi * 16;
      int gr = m0 + row;                       // global row drives the un-swizzle
      af[mi] = *reinterpret_cast<const short8*>(
        &sA[row * 128 + (c >> 3) * 64 + (((c & 7) ^ (gr & 7)) * 8)]);
    }
    #pragma unroll
    for (int ni = 0; ni < 3; ++ni) {
      int row = brow0 + ni * 16;
      int gr = n0 + row;
      bfv[ni] = *reinterpret_cast<const short8*>(
        &sB[row * 128 + (c >> 3) * 64 + (((c & 7) ^ (gr & 7)) * 8)]);
    }
    __builtin_amdgcn_s_setprio(1);
    #pragma unroll
    for (int mi = 0; mi < 4; ++mi)
      #pragma unroll
      for (int ni = 0; ni < 3; ++ni)
        acc[mi][ni] = __builtin_amdgcn_mfma_f32_16x16x32_bf16(af[mi], bfv[ni], acc[mi][ni], 0, 0, 0);
    __builtin_amdgcn_s_setprio(0);
  }

  // ---- spill D tile to LDS as f16, aliasing the staging buffers ----
  __syncthreads();                     // all MFMA operand reads done
  u16* Dt = buf;                       // [128][DTS=200]
  #pragma unroll
  for (int mi = 0; mi < 4; ++mi)
    #pragma unroll
    for (int ni = 0; ni < 3; ++ni) {
      int col = wn * 48 + ni * 16 + r15;
      #pragma unroll
      for (int rg = 0; rg < 4; ++rg) {
        int row = wm * 64 + mi * 16 + g16 * 4 + rg;
        Dt[row * DTS + col] = __builtin_bit_cast(u16, (_Float16)acc[mi][ni][rg]);
      }
    }
  __syncthreads();

  // ---- emit H = diagonal-3 of Dt (f16 packed adds), interior 126x190 ----
  for (int t = tid; t < 126 * 24; t += 512) {    // 126 rows x 24 col-chunks
    int rr = t / 24, c8 = t - rr * 24;
    int grow = m0 + rr;
    if (grow >= 2302) continue;
    int lcol = c8 * 8;
    int lim = NTC - lcol;
    int glim = 2302 - (n0 + lcol);
    lim = lim < glim ? lim : glim;
    if (lim <= 0) continue;
    int base = rr * DTS + lcol;
    half8 a0 = *reinterpret_cast<const half8*>(&Dt[base]);
    half8 b0 = *reinterpret_cast<const half8*>(&Dt[base + DTS]);
    half8 b1 = *reinterpret_cast<const half8*>(&Dt[base + DTS + 8]);
    half8 c0 = *reinterpret_cast<const half8*>(&Dt[base + 2 * DTS]);
    half8 c1 = *reinterpret_cast<const half8*>(&Dt[base + 2 * DTS + 8]);
    half8 s1v = __builtin_shufflevector(b0, b1, 1, 2, 3, 4, 5, 6, 7, 8);
    half8 s2v = __builtin_shufflevector(c0, c1, 2, 3, 4, 5, 6, 7, 8, 9);
    half8 sum = a0 + s1v + s2v;
    u32x4 pk = __builtin_bit_cast(u32x4, sum);
    u16* dst = Hs + (size_t)grow * NPIX + n0 + lcol;
    int nd = lim >= 8 ? 4 : (lim >> 1);          // lim even by construction
    #pragma unroll
    for (int d = 0; d < 4; ++d)
      if (d < nd) *reinterpret_cast<unsigned*>(dst + 2 * d) = pk[d];
  }
}

// ---- kernel 3: packed-f16 stencil, phase-split max/argmax + raw-patch MSE ----
__global__ __launch_bounds__(512) void k_stencil(const u16* __restrict__ H,
                                                 const float* __restrict__ pred,
                                                 const float* __restrict__ targ,
                                                 float* __restrict__ msep) {
  const int bid = blockIdx.x;
  const int b = bid >= NQ ? 1 : 0;
  const int orig = bid - b * NQ;
  const int xcd = orig & 7, pos = orig >> 3;
  const int q = (xcd < 4 ? xcd * 265 : 1060 + (xcd - 4) * 264) + pos;

  const int tid = threadIdx.x, lane = tid & 63, wid = tid >> 6;
  const int qy = q / NHW, qx = q - qy * NHW;
  const int qp = qy * WW + qx;

  const _Float16 ninf = __builtin_bit_cast(_Float16, (u16)0xFC00);
  half8 pmax = {ninf, ninf, ninf, ninf, ninf, ninf, ninf, ninf};

  // ---- phase 1: packed max over all candidates (no index tracking) ----
  #pragma unroll
  for (int it = 0; it < 2; ++it) {             // 552 tasks = kc(2) x ny(46) x cx(6)
    int t = it * 512 + tid;
    if (t < 552) {
      int kc = t / 276; int rem = t - kc * 276;
      int ny = rem / 6, cx = rem - ny * 6;
      const u16* Hs = H + (size_t)(b * 2 + kc) * DSTRIDE;
      int colb = ny * 48 + cx * 8;
      half8 t0 = *reinterpret_cast<const half8*>(Hs + (size_t)qp * NPIX + colb);
      half8 t1 = *reinterpret_cast<const half8*>(Hs + (size_t)(qp + 48) * NPIX + colb + 48);
      half8 t2 = *reinterpret_cast<const half8*>(Hs + (size_t)(qp + 96) * NPIX + colb + 96);
      half8 sm = t0 + t1 + t2;
      if (cx == 5) { sm[6] = ninf; sm[7] = ninf; }   // mask nx=46,47
      pmax = __builtin_elementwise_max(pmax, sm);
    }
  }
  float m = (float)pmax[0];
  #pragma unroll
  for (int e = 1; e < 8; ++e) { float v = (float)pmax[e]; m = v > m ? v : m; }
  #pragma unroll
  for (int off = 1; off < 64; off <<= 1) {
    float o = __shfl_xor(m, off, 64);
    m = o > m ? o : m;
  }
  __shared__ float sv[8];
  __shared__ int si[8];
  __shared__ float rsum[8];
  if (lane == 0) sv[wid] = m;
  __syncthreads();
  float M = sv[0];
  #pragma unroll
  for (int wv = 1; wv < 8; ++wv) M = sv[wv] > M ? sv[wv] : M;

  // ---- phase 2: only threads whose max hit M rescan for first index ----
  int nmin = 0x7fffffff;
  if (m == M) {
    #pragma unroll
    for (int it = 0; it < 2; ++it) {
      int t = it * 512 + tid;
      if (t < 552) {
        int kc = t / 276; int rem = t - kc * 276;
        int ny = rem / 6, cx = rem - ny * 6;
        const u16* Hs = H + (size_t)(b * 2 + kc) * DSTRIDE;
        int colb = ny * 48 + cx * 8;
        half8 t0 = *reinterpret_cast<const half8*>(Hs + (size_t)qp * NPIX + colb);
        half8 t1 = *reinterpret_cast<const half8*>(Hs + (size_t)(qp + 48) * NPIX + colb + 48);
        half8 t2 = *reinterpret_cast<const half8*>(Hs + (size_t)(qp + 96) * NPIX + colb + 96);
        half8 sm = t0 + t1 + t2;
        if (cx == 5) { sm[6] = ninf; sm[7] = ninf; }
        int nbase = kc * NQ + ny * NHW + cx * 8;
        #pragma unroll
        for (int e = 0; e < 8; ++e) {
          float sc = (float)sm[e];
          int n = nbase + e;
          if (sc == M && n < nmin) nmin = n;
        }
      }
    }
  }
  #pragma unroll
  for (int off = 1; off < 64; off <<= 1) {
    int o = __shfl_xor(nmin, off, 64);
    nmin = o < nmin ? o : nmin;
  }
  if (lane == 0) si[wid] = nmin;
  __syncthreads();
  int fi = si[0];
  #pragma unroll
  for (int wv = 1; wv < 8; ++wv) fi = si[wv] < fi ? si[wv] : fi;

  // ---- raw-patch MSE against the selected target patch ----
  int nkc = fi >= NQ ? 1 : 0;
  int ns = fi - nkc * NQ;
  int ny = ns / NHW, nx = ns - ny * NHW;
  const float* P = pred + (size_t)b * CC * HW2;
  const float* T = targ + (size_t)(b * 2 + nkc) * CC * HW2;
  float ssum = 0.f;
  for (int i = tid; i < CC * 9; i += 512) {
    int c = i / 9, sp = i - 9 * c;
    int di = sp / 3, dj = sp - 3 * di;
    float d = P[(size_t)c * HW2 + (qy + di) * WW + qx + dj]
            - T[(size_t)c * HW2 + (ny + di) * WW + nx + dj];
    ssum += d * d;
  }
  #pragma unroll
  for (int off = 1; off < 64; off <<= 1) ssum += __shfl_xor(ssum, off, 64);
  if (lane == 0) rsum[wid] = ssum;
  __syncthreads();
  if (tid == 0) {
    float t = 0.f;
    #pragma unroll
    for (int wv = 0; wv < 8; ++wv) t += rsum[wv];
    msep[b * NQ + q] = t;
  }
}

// ---- kernel 4: final deterministic reduction ----
__global__ void k_final(const float* __restrict__ msep, float* __restrict__ out) {
  int t = threadIdx.x;
  float s = 0.f;
  for (int i = t; i < BATCH * NQ; i += 256) s += msep[i];
  __shared__ float red[256];
  red[t] = s; __syncthreads();
  for (int st = 128; st > 0; st >>= 1) { if (t < st) red[t] += red[t + st]; __syncthreads(); }
  if (t == 0) out[0] = red[0] * (1.0f / 4875264.0f);   // 2*2116*128*9
}

extern "C" void kernel_launch(void* const* d_in, const int* in_sizes, int n_in,
                              void* d_out, int out_size, void* d_ws, size_t ws_size,
                              hipStream_t stream) {
  const float* pred = (const float*)d_in[0];
  const float* targ = (const float*)d_in[1];
  char* ws = (char*)d_ws;

  size_t offP = 0;
  size_t offT = offP + (size_t)2 * NPIX * CC * 2;     // PnT: 1,179,648
  size_t offH = offT + (size_t)4 * NPIX * CC * 2;     // TnT: 2,359,296
  size_t offM = offH + (size_t)4 * DSTRIDE * 2;       // H (4 sets): 42,467,840

  u16*   PnT  = (u16*)(ws + offP);
  u16*   TnT  = (u16*)(ws + offT);
  u16*   Hbuf = (u16*)(ws + offH);
  float* msep = (float*)(ws + offM);                  // total ~46 MB

  k_norm<<<dim3(36, 6), 256, 0, stream>>>(pred, targ, PnT, TnT);
  k_pixdotH<<<dim3(13, 19, 4), 512, 0, stream>>>(PnT, TnT, Hbuf);
  k_stencil<<<dim3(BATCH * NQ), 512, 0, stream>>>(Hbuf, pred, targ, msep);
  k_final<<<1, 256, 0, stream>>>(msep, (float*)d_out);
}

// Round 19
// 67.385 us; speedup vs baseline: 1.9721x; 1.0424x over previous
//
#include <hip/hip_runtime.h>
#include <hip/hip_bf16.h>

typedef unsigned short u16;
typedef __attribute__((ext_vector_type(8))) short short8;
typedef _Float16 half8 __attribute__((ext_vector_type(8)));
typedef __attribute__((ext_vector_type(4))) float f32x4;
typedef __attribute__((ext_vector_type(4))) unsigned int u32x4;

#define CC    128
#define WW    48
#define HW2   2304      // 48*48
#define NHW   46
#define NQ    2116      // 46*46
#define NPIX  2304      // pixels per image
#define DSTRIDE ((size_t)NPIX * NPIX + 64)   // elems per set, +tail pad for vector overrun
#define BATCH 2
#define MT    126       // H rows emitted per tile
#define NTC   190       // H cols emitted per tile
#define DTS   200       // Dt LDS row stride (u16 units)

__device__ __forceinline__ u16 f2bf(float f) {
  union { float f; unsigned u; } x; x.f = f;
  unsigned r = (x.u + 0x7fffu + ((x.u >> 16) & 1u)) >> 16;
  return (u16)r;
}

// ---- kernel 1: per-pixel normalize + transpose to [pix][128c] bf16, chunk-swizzled ----
__global__ __launch_bounds__(256) void k_norm(const float* __restrict__ pred,
                                              const float* __restrict__ targ,
                                              u16* __restrict__ PnT, u16* __restrict__ TnT) {
  const int img = blockIdx.y;          // 0..5 : 0-1 pred, 2-5 target
  const int p0  = blockIdx.x * 64;     // 36 blocks of 64 pixels
  const int tid = threadIdx.x;
  const float* src = img < 2 ? pred + (size_t)img * CC * HW2
                             : targ + (size_t)(img - 2) * CC * HW2;
  u16* out = img < 2 ? PnT + (size_t)img * NPIX * CC
                     : TnT + (size_t)(img - 2) * NPIX * CC;

  __shared__ float sT[64][129];
  __shared__ float sInv[64];

  #pragma unroll
  for (int it = 0; it < 32; ++it) {
    int idx = it * 256 + tid;
    int c = idx >> 6, p = idx & 63;
    sT[p][c] = src[(size_t)c * HW2 + p0 + p];
  }
  __syncthreads();
  if (tid < 64) {
    float s = 0.f;
    for (int c = 0; c < CC; ++c) { float v = sT[tid][c]; s += v * v; }
    sInv[tid] = 1.0f / fmaxf(sqrtf(s), 1e-12f);
  }
  __syncthreads();
  #pragma unroll
  for (int it = 0; it < 4; ++it) {
    int cid = it * 256 + tid;
    int p = cid >> 4, g = cid & 15;
    int r = p0 + p;
    int sc = (g & ~7) | ((g & 7) ^ (r & 7));
    float inv = sInv[p];
    unsigned pack[4];
    #pragma unroll
    for (int e = 0; e < 8; ++e) {
      float v = sT[p][sc * 8 + e] * inv;
      if ((e & 1) == 0) pack[e >> 1] = (unsigned)f2bf(v);
      else              pack[e >> 1] |= ((unsigned)f2bf(v)) << 16;
    }
    u32x4 o; o.x = pack[0]; o.y = pack[1]; o.z = pack[2]; o.w = pack[3];
    *reinterpret_cast<u32x4*>(out + (size_t)r * CC + g * 8) = o;
  }
}

// ---- kernel 2: pixel-dot GEMM (128x192) + in-LDS diagonal-3 epilogue -> H (f16) ----
__global__ __launch_bounds__(512, 2) void k_pixdotH(const u16* __restrict__ PnT, const u16* __restrict__ TnT,
                                                    u16* __restrict__ H) {
  __shared__ u16 buf[40960];           // 80 KB
  u16* sA = buf;                       // 128 rows x 128 K  (2048 slots)
  u16* sB = buf + 16384;               // 192 rows x 128 K  (3072 slots)
  const int nt = blockIdx.x, mt = blockIdx.y, s = blockIdx.z;
  const int tid = threadIdx.x, lane = tid & 63, wid = tid >> 6;
  const int wm = wid >> 2, wn = wid & 3;
  const int r15 = lane & 15, g16 = lane >> 4;
  const int m0 = mt * MT, n0 = nt * NTC;

  const u16* Ab = PnT + (size_t)(s >> 1) * NPIX * CC;
  const u16* Bb = TnT + (size_t)s * NPIX * CC;
  u16* Hs = H + (size_t)s * DSTRIDE;

  #pragma unroll
  for (int i = 0; i < 4; ++i) {        // A: 2048 slots
    int sl = i * 512 + tid;
    int row = m0 + (sl >> 4); row = row < 2303 ? row : 2303;
    __builtin_amdgcn_global_load_lds(
      (const __attribute__((address_space(1))) unsigned*)(Ab + (size_t)row * CC + (sl & 15) * 8),
      (__attribute__((address_space(3))) unsigned*)&sA[sl * 8], 16, 0, 0);
  }
  #pragma unroll
  for (int i = 0; i < 6; ++i) {        // B: 3072 slots
    int sl = i * 512 + tid;
    int row = n0 + (sl >> 4); row = row < 2303 ? row : 2303;
    __builtin_amdgcn_global_load_lds(
      (const __attribute__((address_space(1))) unsigned*)(Bb + (size_t)row * CC + (sl & 15) * 8),
      (__attribute__((address_space(3))) unsigned*)&sB[sl * 8], 16, 0, 0);
  }

  f32x4 acc[4][3];
  const f32x4 z4 = {0.f, 0.f, 0.f, 0.f};
  #pragma unroll
  for (int i = 0; i < 4; ++i)
    #pragma unroll
    for (int j = 0; j < 3; ++j) acc[i][j] = z4;

  asm volatile("s_waitcnt vmcnt(0)" ::: "memory");
  __builtin_amdgcn_s_barrier();

  const int arow0 = wm * 64 + r15;
  const int brow0 = wn * 48 + r15;
  #pragma unroll
  for (int ks = 0; ks < 4; ++ks) {
    const int c = ks * 4 + g16;
    short8 af[4], bfv[3];
    #pragma unroll
    for (int mi = 0; mi < 4; ++mi) {
      int row = arow0 + mi * 16;
      int gr = m0 + row;                       // global row drives the un-swizzle
      af[mi] = *reinterpret_cast<const short8*>(
        &sA[row * 128 + (c >> 3) * 64 + (((c & 7) ^ (gr & 7)) * 8)]);
    }
    #pragma unroll
    for (int ni = 0; ni < 3; ++ni) {
      int row = brow0 + ni * 16;
      int gr = n0 + row;
      bfv[ni] = *reinterpret_cast<const short8*>(
        &sB[row * 128 + (c >> 3) * 64 + (((c & 7) ^ (gr & 7)) * 8)]);
    }
    __builtin_amdgcn_s_setprio(1);
    #pragma unroll
    for (int mi = 0; mi < 4; ++mi)
      #pragma unroll
      for (int ni = 0; ni < 3; ++ni)
        acc[mi][ni] = __builtin_amdgcn_mfma_f32_16x16x32_bf16(af[mi], bfv[ni], acc[mi][ni], 0, 0, 0);
    __builtin_amdgcn_s_setprio(0);
  }

  // ---- spill D tile to LDS as f16, aliasing the staging buffers ----
  __syncthreads();                     // all MFMA operand reads done
  u16* Dt = buf;                       // [128][DTS=200]
  #pragma unroll
  for (int mi = 0; mi < 4; ++mi)
    #pragma unroll
    for (int ni = 0; ni < 3; ++ni) {
      int col = wn * 48 + ni * 16 + r15;
      #pragma unroll
      for (int rg = 0; rg < 4; ++rg) {
        int row = wm * 64 + mi * 16 + g16 * 4 + rg;
        Dt[row * DTS + col] = __builtin_bit_cast(u16, (_Float16)acc[mi][ni][rg]);
      }
    }
  __syncthreads();

  // ---- emit H = diagonal-3 of Dt (f16 packed adds), interior 126x190 ----
  for (int t = tid; t < 126 * 24; t += 512) {    // 126 rows x 24 col-chunks
    int rr = t / 24, c8 = t - rr * 24;
    int grow = m0 + rr;
    if (grow >= 2302) continue;
    int lcol = c8 * 8;
    int lim = NTC - lcol;
    int glim = 2302 - (n0 + lcol);
    lim = lim < glim ? lim : glim;
    if (lim <= 0) continue;
    int base = rr * DTS + lcol;
    half8 a0 = *reinterpret_cast<const half8*>(&Dt[base]);
    half8 b0 = *reinterpret_cast<const half8*>(&Dt[base + DTS]);
    half8 b1 = *reinterpret_cast<const half8*>(&Dt[base + DTS + 8]);
    half8 c0 = *reinterpret_cast<const half8*>(&Dt[base + 2 * DTS]);
    half8 c1 = *reinterpret_cast<const half8*>(&Dt[base + 2 * DTS + 8]);
    half8 s1v = __builtin_shufflevector(b0, b1, 1, 2, 3, 4, 5, 6, 7, 8);
    half8 s2v = __builtin_shufflevector(c0, c1, 2, 3, 4, 5, 6, 7, 8, 9);
    half8 sum = a0 + s1v + s2v;
    u32x4 pk = __builtin_bit_cast(u32x4, sum);
    u16* dst = Hs + (size_t)grow * NPIX + n0 + lcol;
    int nd = lim >= 8 ? 4 : (lim >> 1);          // lim even by construction
    #pragma unroll
    for (int d = 0; d < 4; ++d)
      if (d < nd) *reinterpret_cast<unsigned*>(dst + 2 * d) = pk[d];
  }
}

// ---- kernel 3: packed-f16 stencil, TWO adjacent queries per block (one per half) ----
__global__ __launch_bounds__(512) void k_stencil(const u16* __restrict__ H,
                                                 const float* __restrict__ pred,
                                                 const float* __restrict__ targ,
                                                 float* __restrict__ msep) {
  // 2116 blocks: b half, then XCD-chunked pair index j over 1058 (q=132,r=2);
  // the two queries (2j, 2j+1) share nearly all H rows -> L2/L1 friendly.
  const int bid = blockIdx.x;
  const int b = bid >= 1058 ? 1 : 0;
  const int j = bid - b * 1058;
  const int xcd = j & 7, pos = j >> 3;
  const int jswz = (xcd < 2 ? xcd * 133 : 266 + (xcd - 2) * 132) + pos;

  const int tid = threadIdx.x;
  const int hid = tid >> 8, htid = tid & 255;    // half (query), index in half
  const int lane = tid & 63, wid = tid >> 6;     // waves 0-3 = half 0, 4-7 = half 1
  const int q = jswz * 2 + hid;
  const int qy = q / NHW, qx = q - qy * NHW;
  const int qp = qy * WW + qx;

  const _Float16 ninf = __builtin_bit_cast(_Float16, (u16)0xFC00);
  const half8 ninf8 = {ninf, ninf, ninf, ninf, ninf, ninf, ninf, ninf};

  half8 smc[3];
  int nb[3];
  smc[0] = ninf8; smc[1] = ninf8; smc[2] = ninf8;
  nb[0] = nb[1] = nb[2] = 0;

  half8 pmax = ninf8;
  // ---- phase 1: packed max over 552 tasks (kc x ny x cx), cache sm in regs ----
  #pragma unroll
  for (int it = 0; it < 3; ++it) {
    int t = it * 256 + htid;
    if (t < 552) {
      int kc = t / 276; int rem = t - kc * 276;
      int ny = rem / 6, cx = rem - ny * 6;
      const u16* Hs = H + (size_t)(b * 2 + kc) * DSTRIDE;
      int colb = ny * 48 + cx * 8;
      half8 t0 = *reinterpret_cast<const half8*>(Hs + (size_t)qp * NPIX + colb);
      half8 t1 = *reinterpret_cast<const half8*>(Hs + (size_t)(qp + 48) * NPIX + colb + 48);
      half8 t2 = *reinterpret_cast<const half8*>(Hs + (size_t)(qp + 96) * NPIX + colb + 96);
      half8 sm = t0 + t1 + t2;
      if (cx == 5) { sm[6] = ninf; sm[7] = ninf; }   // mask nx=46,47
      smc[it] = sm;
      nb[it] = kc * NQ + ny * NHW + cx * 8;
      pmax = __builtin_elementwise_max(pmax, sm);
    }
  }
  float m = (float)pmax[0];
  #pragma unroll
  for (int e = 1; e < 8; ++e) { float v = (float)pmax[e]; m = v > m ? v : m; }
  #pragma unroll
  for (int off = 1; off < 64; off <<= 1) {
    float o = __shfl_xor(m, off, 64);
    m = o > m ? o : m;
  }
  __shared__ float sv[8];
  __shared__ int si[8];
  __shared__ float rsum[8];
  if (lane == 0) sv[wid] = m;
  __syncthreads();
  float M = sv[hid * 4];
  #pragma unroll
  for (int wv = 1; wv < 4; ++wv) { float v = sv[hid * 4 + wv]; M = v > M ? v : M; }

  // ---- phase 2: threads whose max hit M rescan their cached regs ----
  int nmin = 0x7fffffff;
  if (m == M) {
    #pragma unroll
    for (int it = 0; it < 3; ++it) {
      #pragma unroll
      for (int e = 0; e < 8; ++e) {
        float sc = (float)smc[it][e];
        int n = nb[it] + e;
        if (sc == M && n < nmin) nmin = n;
      }
    }
  }
  #pragma unroll
  for (int off = 1; off < 64; off <<= 1) {
    int o = __shfl_xor(nmin, off, 64);
    nmin = o < nmin ? o : nmin;
  }
  if (lane == 0) si[wid] = nmin;
  __syncthreads();
  int fi = si[hid * 4];
  #pragma unroll
  for (int wv = 1; wv < 4; ++wv) { int v = si[hid * 4 + wv]; fi = v < fi ? v : fi; }

  // ---- raw-patch MSE against the selected target patch ----
  int nkc = fi >= NQ ? 1 : 0;
  int ns = fi - nkc * NQ;
  ns = ns < NQ ? ns : NQ - 1;
  int ny = ns / NHW, nx = ns - ny * NHW;
  const float* P = pred + (size_t)b * CC * HW2;
  const float* T = targ + (size_t)(b * 2 + nkc) * CC * HW2;
  float ssum = 0.f;
  for (int i = htid; i < CC * 9; i += 256) {
    int c = i / 9, sp = i - 9 * c;
    int di = sp / 3, dj = sp - 3 * di;
    float d = P[(size_t)c * HW2 + (qy + di) * WW + qx + dj]
            - T[(size_t)c * HW2 + (ny + di) * WW + nx + dj];
    ssum += d * d;
  }
  #pragma unroll
  for (int off = 1; off < 64; off <<= 1) ssum += __shfl_xor(ssum, off, 64);
  if (lane == 0) rsum[wid] = ssum;
  __syncthreads();
  if (htid == 0) {
    float t = 0.f;
    #pragma unroll
    for (int wv = 0; wv < 4; ++wv) t += rsum[hid * 4 + wv];
    msep[b * NQ + q] = t;
  }
}

// ---- kernel 4: final deterministic reduction ----
__global__ void k_final(const float* __restrict__ msep, float* __restrict__ out) {
  int t = threadIdx.x;
  float s = 0.f;
  for (int i = t; i < BATCH * NQ; i += 256) s += msep[i];
  __shared__ float red[256];
  red[t] = s; __syncthreads();
  for (int st = 128; st > 0; st >>= 1) { if (t < st) red[t] += red[t + st]; __syncthreads(); }
  if (t == 0) out[0] = red[0] * (1.0f / 4875264.0f);   // 2*2116*128*9
}

extern "C" void kernel_launch(void* const* d_in, const int* in_sizes, int n_in,
                              void* d_out, int out_size, void* d_ws, size_t ws_size,
                              hipStream_t stream) {
  const float* pred = (const float*)d_in[0];
  const float* targ = (const float*)d_in[1];
  char* ws = (char*)d_ws;

  size_t offP = 0;
  size_t offT = offP + (size_t)2 * NPIX * CC * 2;     // PnT: 1,179,648
  size_t offH = offT + (size_t)4 * NPIX * CC * 2;     // TnT: 2,359,296
  size_t offM = offH + (size_t)4 * DSTRIDE * 2;       // H (4 sets): 42,467,840

  u16*   PnT  = (u16*)(ws + offP);
  u16*   TnT  = (u16*)(ws + offT);
  u16*   Hbuf = (u16*)(ws + offH);
  float* msep = (float*)(ws + offM);                  // total ~46 MB

  k_norm<<<dim3(36, 6), 256, 0, stream>>>(pred, targ, PnT, TnT);
  k_pixdotH<<<dim3(13, 19, 4), 512, 0, stream>>>(PnT, TnT, Hbuf);
  k_stencil<<<dim3(2 * 1058), 512, 0, stream>>>(Hbuf, pred, targ, msep);
  k_final<<<1, 256, 0, stream>>>(msep, (float*)d_out);
}

// Round 21
// 65.700 us; speedup vs baseline: 2.0227x; 1.0257x over previous
//
#include <hip/hip_runtime.h>
#include <hip/hip_bf16.h>

typedef unsigned short u16;
typedef __attribute__((ext_vector_type(8))) short short8;
typedef _Float16 half8 __attribute__((ext_vector_type(8)));
typedef __attribute__((ext_vector_type(4))) float f32x4;
typedef __attribute__((ext_vector_type(4))) unsigned int u32x4;

#define CC    128
#define WW    48
#define HW2   2304      // 48*48
#define NHW   46
#define NQ    2116      // 46*46
#define NPIX  2304      // pixels per image
#define DSTRIDE ((size_t)NPIX * NPIX + 64)   // elems per set, +tail pad for vector overrun
#define BATCH 2
#define MT    126       // H rows emitted per tile
#define NTC   190       // H cols emitted per tile
#define DTS   200       // Dt LDS row stride (u16 units)

__device__ __forceinline__ u16 f2bf(float f) {
  union { float f; unsigned u; } x; x.f = f;
  unsigned r = (x.u + 0x7fffu + ((x.u >> 16) & 1u)) >> 16;
  return (u16)r;
}

// ---- kernel 1: per-pixel normalize + transpose to [pix][128c] bf16, chunk-swizzled ----
__global__ __launch_bounds__(256) void k_norm(const float* __restrict__ pred,
                                              const float* __restrict__ targ,
                                              u16* __restrict__ PnT, u16* __restrict__ TnT) {
  const int img = blockIdx.y;          // 0..5 : 0-1 pred, 2-5 target
  const int p0  = blockIdx.x * 64;     // 36 blocks of 64 pixels
  const int tid = threadIdx.x;
  const float* src = img < 2 ? pred + (size_t)img * CC * HW2
                             : targ + (size_t)(img - 2) * CC * HW2;
  u16* out = img < 2 ? PnT + (size_t)img * NPIX * CC
                     : TnT + (size_t)(img - 2) * NPIX * CC;

  __shared__ float sT[64][129];
  __shared__ float sInv[64];

  #pragma unroll
  for (int it = 0; it < 32; ++it) {
    int idx = it * 256 + tid;
    int c = idx >> 6, p = idx & 63;
    sT[p][c] = src[(size_t)c * HW2 + p0 + p];
  }
  __syncthreads();
  if (tid < 64) {
    float s = 0.f;
    for (int c = 0; c < CC; ++c) { float v = sT[tid][c]; s += v * v; }
    sInv[tid] = 1.0f / fmaxf(sqrtf(s), 1e-12f);
  }
  __syncthreads();
  #pragma unroll
  for (int it = 0; it < 4; ++it) {
    int cid = it * 256 + tid;
    int p = cid >> 4, g = cid & 15;
    int r = p0 + p;
    int sc = (g & ~7) | ((g & 7) ^ (r & 7));
    float inv = sInv[p];
    unsigned pack[4];
    #pragma unroll
    for (int e = 0; e < 8; ++e) {
      float v = sT[p][sc * 8 + e] * inv;
      if ((e & 1) == 0) pack[e >> 1] = (unsigned)f2bf(v);
      else              pack[e >> 1] |= ((unsigned)f2bf(v)) << 16;
    }
    u32x4 o; o.x = pack[0]; o.y = pack[1]; o.z = pack[2]; o.w = pack[3];
    *reinterpret_cast<u32x4*>(out + (size_t)r * CC + g * 8) = o;
  }
}

// ---- kernel 2: pixel-dot GEMM (128x192), split-K pipelined (half-contiguous LDS),
//      in-LDS diagonal-3 epilogue -> H (f16) ----
__global__ __launch_bounds__(512, 2) void k_pixdotH(const u16* __restrict__ PnT, const u16* __restrict__ TnT,
                                                    u16* __restrict__ H) {
  __shared__ u16 buf[40960];           // 80 KB
  // per-K-half contiguous regions (global_load_lds dest must be lane-linear):
  u16* sAh[2] = { buf, buf + 8192 };               // each 128 rows x 8 chunks (1024 slots)
  u16* sBh[2] = { buf + 16384, buf + 28672 };      // each 192 rows x 8 chunks (1536 slots)
  const int nt = blockIdx.x, mt = blockIdx.y, s = blockIdx.z;
  const int tid = threadIdx.x, lane = tid & 63, wid = tid >> 6;
  const int wm = wid >> 2, wn = wid & 3;
  const int r15 = lane & 15, g16 = lane >> 4;
  const int m0 = mt * MT, n0 = nt * NTC;

  const u16* Ab = PnT + (size_t)(s >> 1) * NPIX * CC;
  const u16* Bb = TnT + (size_t)s * NPIX * CC;
  u16* Hs = H + (size_t)s * DSTRIDE;

  auto stageA = [&](int h) {           // one K-half of A: 1024 slots, 2/thread, linear dest
    #pragma unroll
    for (int i = 0; i < 2; ++i) {
      int idx = i * 512 + tid;
      int row = idx >> 3, lc = idx & 7;
      int grow = m0 + row; grow = grow < 2303 ? grow : 2303;
      __builtin_amdgcn_global_load_lds(
        (const __attribute__((address_space(1))) unsigned*)(Ab + (size_t)grow * CC + (h * 8 + lc) * 8),
        (__attribute__((address_space(3))) unsigned*)&sAh[h][idx * 8], 16, 0, 0);
    }
  };
  auto stageB = [&](int h) {           // one K-half of B: 1536 slots, 3/thread, linear dest
    #pragma unroll
    for (int i = 0; i < 3; ++i) {
      int idx = i * 512 + tid;
      int row = idx >> 3, lc = idx & 7;
      int grow = n0 + row; grow = grow < 2303 ? grow : 2303;
      __builtin_amdgcn_global_load_lds(
        (const __attribute__((address_space(1))) unsigned*)(Bb + (size_t)grow * CC + (h * 8 + lc) * 8),
        (__attribute__((address_space(3))) unsigned*)&sBh[h][idx * 8], 16, 0, 0);
    }
  };

  f32x4 acc[4][3];
  const f32x4 z4 = {0.f, 0.f, 0.f, 0.f};
  #pragma unroll
  for (int i = 0; i < 4; ++i)
    #pragma unroll
    for (int j = 0; j < 3; ++j) acc[i][j] = z4;

  const int arow0 = wm * 64 + r15;
  const int brow0 = wn * 48 + r15;

  auto mfmaPair = [&](int ks0) {       // two K-steps (one K-half)
    #pragma unroll
    for (int ks = ks0; ks < ks0 + 2; ++ks) {
      const int c = ks * 4 + g16;
      const int h = c >> 3, lc = c & 7;
      short8 af[4], bfv[3];
      #pragma unroll
      for (int mi = 0; mi < 4; ++mi) {
        int row = arow0 + mi * 16;
        int gr = m0 + row;                     // global row drives the un-swizzle
        af[mi] = *reinterpret_cast<const short8*>(
          &sAh[h][row * 64 + ((lc ^ (gr & 7)) * 8)]);
      }
      #pragma unroll
      for (int ni = 0; ni < 3; ++ni) {
        int row = brow0 + ni * 16;
        int gr = n0 + row;
        bfv[ni] = *reinterpret_cast<const short8*>(
          &sBh[h][row * 64 + ((lc ^ (gr & 7)) * 8)]);
      }
      __builtin_amdgcn_s_setprio(1);
      #pragma unroll
      for (int mi = 0; mi < 4; ++mi)
        #pragma unroll
        for (int ni = 0; ni < 3; ++ni)
          acc[mi][ni] = __builtin_amdgcn_mfma_f32_16x16x32_bf16(af[mi], bfv[ni], acc[mi][ni], 0, 0, 0);
      __builtin_amdgcn_s_setprio(0);
    }
  };

  stageA(0); stageB(0);
  asm volatile("s_waitcnt vmcnt(0)" ::: "memory");
  __builtin_amdgcn_s_barrier();        // half-0 landed for all waves
  stageA(1); stageB(1);                // half-1 in flight under MFMA issue
  mfmaPair(0);                         // K-steps 0,1 (chunks 0..7)
  asm volatile("s_waitcnt vmcnt(0)" ::: "memory");
  __builtin_amdgcn_s_barrier();        // half-1 landed
  mfmaPair(2);                         // K-steps 2,3 (chunks 8..15)

  // ---- spill D tile to LDS as f16, aliasing the staging buffers ----
  __syncthreads();                     // all MFMA operand reads done
  u16* Dt = buf;                       // [128][DTS=200]
  #pragma unroll
  for (int mi = 0; mi < 4; ++mi)
    #pragma unroll
    for (int ni = 0; ni < 3; ++ni) {
      int col = wn * 48 + ni * 16 + r15;
      #pragma unroll
      for (int rg = 0; rg < 4; ++rg) {
        int row = wm * 64 + mi * 16 + g16 * 4 + rg;
        Dt[row * DTS + col] = __builtin_bit_cast(u16, (_Float16)acc[mi][ni][rg]);
      }
    }
  __syncthreads();

  // ---- emit H = diagonal-3 of Dt (f16 packed adds), interior 126x190 ----
  for (int t = tid; t < 126 * 24; t += 512) {    // 126 rows x 24 col-chunks
    int rr = t / 24, c8 = t - rr * 24;
    int grow = m0 + rr;
    if (grow >= 2302) continue;
    if ((grow % 48) >= 46) continue;             // rows never read by any tap
    int lcol = c8 * 8;
    int lim = NTC - lcol;
    int glim = 2302 - (n0 + lcol);
    lim = lim < glim ? lim : glim;
    if (lim <= 0) continue;
    int base = rr * DTS + lcol;
    half8 a0 = *reinterpret_cast<const half8*>(&Dt[base]);
    half8 b0 = *reinterpret_cast<const half8*>(&Dt[base + DTS]);
    half8 b1 = *reinterpret_cast<const half8*>(&Dt[base + DTS + 8]);
    half8 c0 = *reinterpret_cast<const half8*>(&Dt[base + 2 * DTS]);
    half8 c1 = *reinterpret_cast<const half8*>(&Dt[base + 2 * DTS + 8]);
    half8 s1v = __builtin_shufflevector(b0, b1, 1, 2, 3, 4, 5, 6, 7, 8);
    half8 s2v = __builtin_shufflevector(c0, c1, 2, 3, 4, 5, 6, 7, 8, 9);
    half8 sum = a0 + s1v + s2v;
    u32x4 pk = __builtin_bit_cast(u32x4, sum);
    u16* dst = Hs + (size_t)grow * NPIX + n0 + lcol;
    int nd = lim >= 8 ? 4 : (lim >> 1);          // lim even by construction
    #pragma unroll
    for (int d = 0; d < 4; ++d)
      if (d < nd) *reinterpret_cast<unsigned*>(dst + 2 * d) = pk[d];
  }
}

// ---- kernel 3: packed-f16 stencil, TWO adjacent queries per block (one per half) ----
__global__ __launch_bounds__(512) void k_stencil(const u16* __restrict__ H,
                                                 const float* __restrict__ pred,
                                                 const float* __restrict__ targ,
                                                 float* __restrict__ msep) {
  // 2116 blocks: b half, then XCD-chunked pair index j over 1058 (q=132,r=2);
  // the two queries (2j, 2j+1) share nearly all H rows -> L2/L1 friendly.
  const int bid = blockIdx.x;
  const int b = bid >= 1058 ? 1 : 0;
  const int j = bid - b * 1058;
  const int xcd = j & 7, pos = j >> 3;
  const int jswz = (xcd < 2 ? xcd * 133 : 266 + (xcd - 2) * 132) + pos;

  const int tid = threadIdx.x;
  const int hid = tid >> 8, htid = tid & 255;    // half (query), index in half
  const int lane = tid & 63, wid = tid >> 6;     // waves 0-3 = half 0, 4-7 = half 1
  const int q = jswz * 2 + hid;
  const int qy = q / NHW, qx = q - qy * NHW;
  const int qp = qy * WW + qx;

  const _Float16 ninf = __builtin_bit_cast(_Float16, (u16)0xFC00);
  const half8 ninf8 = {ninf, ninf, ninf, ninf, ninf, ninf, ninf, ninf};

  half8 smc[3];
  int nb[3];
  smc[0] = ninf8; smc[1] = ninf8; smc[2] = ninf8;
  nb[0] = nb[1] = nb[2] = 0;

  half8 pmax = ninf8;
  // ---- phase 1: packed max over 552 tasks (kc x ny x cx), cache sm in regs ----
  #pragma unroll
  for (int it = 0; it < 3; ++it) {
    int t = it * 256 + htid;
    if (t < 552) {
      int kc = t / 276; int rem = t - kc * 276;
      int ny = rem / 6, cx = rem - ny * 6;
      const u16* Hs = H + (size_t)(b * 2 + kc) * DSTRIDE;
      int colb = ny * 48 + cx * 8;
      half8 t0 = *reinterpret_cast<const half8*>(Hs + (size_t)qp * NPIX + colb);
      half8 t1 = *reinterpret_cast<const half8*>(Hs + (size_t)(qp + 48) * NPIX + colb + 48);
      half8 t2 = *reinterpret_cast<const half8*>(Hs + (size_t)(qp + 96) * NPIX + colb + 96);
      half8 sm = t0 + t1 + t2;
      if (cx == 5) { sm[6] = ninf; sm[7] = ninf; }   // mask nx=46,47
      smc[it] = sm;
      nb[it] = kc * NQ + ny * NHW + cx * 8;
      pmax = __builtin_elementwise_max(pmax, sm);
    }
  }
  float m = (float)pmax[0];
  #pragma unroll
  for (int e = 1; e < 8; ++e) { float v = (float)pmax[e]; m = v > m ? v : m; }
  #pragma unroll
  for (int off = 1; off < 64; off <<= 1) {
    float o = __shfl_xor(m, off, 64);
    m = o > m ? o : m;
  }
  __shared__ float sv[8];
  __shared__ int si[8];
  __shared__ float rsum[8];
  if (lane == 0) sv[wid] = m;
  __syncthreads();
  float M = sv[hid * 4];
  #pragma unroll
  for (int wv = 1; wv < 4; ++wv) { float v = sv[hid * 4 + wv]; M = v > M ? v : M; }

  // ---- phase 2: threads whose max hit M rescan their cached regs ----
  int nmin = 0x7fffffff;
  if (m == M) {
    #pragma unroll
    for (int it = 0; it < 3; ++it) {
      #pragma unroll
      for (int e = 0; e < 8; ++e) {
        float sc = (float)smc[it][e];
        int n = nb[it] + e;
        if (sc == M && n < nmin) nmin = n;
      }
    }
  }
  #pragma unroll
  for (int off = 1; off < 64; off <<= 1) {
    int o = __shfl_xor(nmin, off, 64);
    nmin = o < nmin ? o : nmin;
  }
  if (lane == 0) si[wid] = nmin;
  __syncthreads();
  int fi = si[hid * 4];
  #pragma unroll
  for (int wv = 1; wv < 4; ++wv) { int v = si[hid * 4 + wv]; fi = v < fi ? v : fi; }

  // ---- raw-patch MSE against the selected target patch ----
  int nkc = fi >= NQ ? 1 : 0;
  int ns = fi - nkc * NQ;
  ns = ns < NQ ? ns : NQ - 1;
  int ny = ns / NHW, nx = ns - ny * NHW;
  const float* P = pred + (size_t)b * CC * HW2;
  const float* T = targ + (size_t)(b * 2 + nkc) * CC * HW2;
  float ssum = 0.f;
  for (int i = htid; i < CC * 9; i += 256) {
    int c = i / 9, sp = i - 9 * c;
    int di = sp / 3, dj = sp - 3 * di;
    float d = P[(size_t)c * HW2 + (qy + di) * WW + qx + dj]
            - T[(size_t)c * HW2 + (ny + di) * WW + nx + dj];
    ssum += d * d;
  }
  #pragma unroll
  for (int off = 1; off < 64; off <<= 1) ssum += __shfl_xor(ssum, off, 64);
  if (lane == 0) rsum[wid] = ssum;
  __syncthreads();
  if (htid == 0) {
    float t = 0.f;
    #pragma unroll
    for (int wv = 0; wv < 4; ++wv) t += rsum[hid * 4 + wv];
    msep[b * NQ + q] = t;
  }
}

// ---- kernel 4: final deterministic reduction ----
__global__ void k_final(const float* __restrict__ msep, float* __restrict__ out) {
  int t = threadIdx.x;
  float s = 0.f;
  for (int i = t; i < BATCH * NQ; i += 256) s += msep[i];
  __shared__ float red[256];
  red[t] = s; __syncthreads();
  for (int st = 128; st > 0; st >>= 1) { if (t < st) red[t] += red[t + st]; __syncthreads(); }
  if (t == 0) out[0] = red[0] * (1.0f / 4875264.0f);   // 2*2116*128*9
}

extern "C" void kernel_launch(void* const* d_in, const int* in_sizes, int n_in,
                              void* d_out, int out_size, void* d_ws, size_t ws_size,
                              hipStream_t stream) {
  const float* pred = (const float*)d_in[0];
  const float* targ = (const float*)d_in[1];
  char* ws = (char*)d_ws;

  size_t offP = 0;
  size_t offT = offP + (size_t)2 * NPIX * CC * 2;     // PnT: 1,179,648
  size_t offH = offT + (size_t)4 * NPIX * CC * 2;     // TnT: 2,359,296
  size_t offM = offH + (size_t)4 * DSTRIDE * 2;       // H (4 sets): 42,467,840

  u16*   PnT  = (u16*)(ws + offP);
  u16*   TnT  = (u16*)(ws + offT);
  u16*   Hbuf = (u16*)(ws + offH);
  float* msep = (float*)(ws + offM);                  // total ~46 MB

  k_norm<<<dim3(36, 6), 256, 0, stream>>>(pred, targ, PnT, TnT);
  k_pixdotH<<<dim3(13, 19, 4), 512, 0, stream>>>(PnT, TnT, Hbuf);
  k_stencil<<<dim3(2 * 1058), 512, 0, stream>>>(Hbuf, pred, targ, msep);
  k_final<<<1, 256, 0, stream>>>(msep, (float*)d_out);
}